// Round 5
// baseline (1670.765 us; speedup 1.0000x reference)
//
#include <hip/hip_runtime.h>
#include <hip/hip_bf16.h>
#include <math.h>

#define S 2048
#define NH 16
#define DIM 2048
#define QK_NOPE 128
#define QK_ROPE 64
#define QK_HD 192
#define V_HD 128
#define Q_LORA 1536
#define KV_LORA 512
#define IDX_HD 128
#define SM_SCALE 0.07216878364870323f
#define SCHUNK 512
#define PADK 40
#define XPLD 2256   // packed x-proj output row stride: [qr 1536 | kvp 576 | ikf 128 | iw 16]
#define QLD 5120    // packed qr-proj output row stride: [q 3072 | iqf 2048]
#define XPLD_PAD 2304  // B rows padded to 128 multiple for the x-proj GEMM

typedef __hip_bfloat16 bf16;
typedef unsigned short ushort_t;
typedef __attribute__((ext_vector_type(8))) short short8;
typedef __attribute__((ext_vector_type(4))) float f32x4;

__device__ __forceinline__ f32x4 mfma_bf16(short8 a, short8 b, f32x4 c) {
    return __builtin_amdgcn_mfma_f32_16x16x32_bf16(a, b, c, 0, 0, 0);
}
__device__ __forceinline__ void async16(const void* g, void* l) {
    __builtin_amdgcn_global_load_lds((const __attribute__((address_space(1))) void*)g,
                                     (__attribute__((address_space(3))) void*)l, 16, 0, 0);
}
__device__ __forceinline__ unsigned short f2bf(float f) {  // RNE
    unsigned int u = __float_as_uint(f);
    return (unsigned short)((u + 0x7fff + ((u >> 16) & 1)) >> 16);
}
__device__ __forceinline__ float bf2f(unsigned short b) {
    return __uint_as_float(((unsigned int)b) << 16);
}

// ---------------- fp32 -> bf16 hi/lo split (packed, n4 = elems/4) ----------------
__global__ __launch_bounds__(256) void split_kernel(const float* __restrict__ in, ushort_t* __restrict__ hi,
                                                    ushort_t* __restrict__ lo, int n4) {
    int idx = blockIdx.x * 256 + threadIdx.x;
    if (idx >= n4) return;
    float4 v = ((const float4*)in)[idx];
    ushort4 h, l;
    h.x = f2bf(v.x); l.x = f2bf(v.x - bf2f(h.x));
    h.y = f2bf(v.y); l.y = f2bf(v.y - bf2f(h.y));
    h.z = f2bf(v.z); l.z = f2bf(v.z - bf2f(h.z));
    h.w = f2bf(v.w); l.w = f2bf(v.w - bf2f(h.w));
    ((ushort4*)hi)[idx] = h;
    ((ushort4*)lo)[idx] = l;
}

// ---------------- strided split of kv_b V-half: w2[h][128][512] <- kv_b[h*256+128+r][512] ----------------
__global__ __launch_bounds__(256) void splitw2_kernel(const float* __restrict__ kv_b,
                                                      ushort_t* __restrict__ w2h, ushort_t* __restrict__ w2l) {
    int idx = blockIdx.x * 256 + threadIdx.x;       // 262144 quads
    int h = idx >> 14, rem = idx & 16383;
    int row = rem >> 7, c4 = (rem & 127) * 4;
    float4 v = *(const float4*)(kv_b + ((size_t)(h * 256 + 128 + row)) * 512 + c4);
    ushort4 hh, ll;
    hh.x = f2bf(v.x); ll.x = f2bf(v.x - bf2f(hh.x));
    hh.y = f2bf(v.y); ll.y = f2bf(v.y - bf2f(hh.y));
    hh.z = f2bf(v.z); ll.z = f2bf(v.z - bf2f(hh.z));
    hh.w = f2bf(v.w); ll.w = f2bf(v.w - bf2f(hh.w));
    *(ushort4*)(w2h + ((size_t)(h * 128 + row)) * 512 + c4) = hh;
    *(ushort4*)(w2l + ((size_t)(h * 128 + row)) * 512 + c4) = ll;
}

// ---------------- pre-split bf16x3 MFMA GEMM: C[M,N] = (Ah+Al)[M,K] @ (Bh+Bl)[N,K]^T ----------------
__global__ __launch_bounds__(256) void gemm3_lds(const ushort_t* __restrict__ Ah, const ushort_t* __restrict__ Al,
                                                 const ushort_t* __restrict__ Bh, const ushort_t* __restrict__ Bl,
                                                 float* __restrict__ C, int M, int N, int K) {
    __shared__ ushort_t sAh[128 * 32], sAl[128 * 32], sBh[128 * 32], sBl[128 * 32];
    const int tid = threadIdx.x;
    const int bm = blockIdx.y * 128, bn = blockIdx.x * 128;
    const int w = tid >> 6, lane = tid & 63;
    const int wm = (w >> 1) * 64, wn = (w & 1) * 64;
    const int fr = lane & 15, fk = (lane >> 4) * 8;
    const int srow = tid >> 2, skc = (tid & 3) * 8;
    f32x4 acc[4][4];
    for (int i = 0; i < 4; ++i)
        for (int j = 0; j < 4; ++j) acc[i][j] = f32x4{0.f, 0.f, 0.f, 0.f};
    const ushort_t* pAh0 = Ah + (size_t)(bm + srow) * K + skc;
    const ushort_t* pAh1 = Ah + (size_t)(bm + 64 + srow) * K + skc;
    const ushort_t* pAl0 = Al + (size_t)(bm + srow) * K + skc;
    const ushort_t* pAl1 = Al + (size_t)(bm + 64 + srow) * K + skc;
    const ushort_t* pBh0 = Bh + (size_t)(bn + srow) * K + skc;
    const ushort_t* pBh1 = Bh + (size_t)(bn + 64 + srow) * K + skc;
    const ushort_t* pBl0 = Bl + (size_t)(bn + srow) * K + skc;
    const ushort_t* pBl1 = Bl + (size_t)(bn + 64 + srow) * K + skc;
    ushort_t* dA0 = &sAh[srow * 32 + skc];
    ushort_t* dA1 = &sAh[(64 + srow) * 32 + skc];
    ushort_t* dAl0 = &sAl[srow * 32 + skc];
    ushort_t* dAl1 = &sAl[(64 + srow) * 32 + skc];
    ushort_t* dB0 = &sBh[srow * 32 + skc];
    ushort_t* dB1 = &sBh[(64 + srow) * 32 + skc];
    ushort_t* dBl0 = &sBl[srow * 32 + skc];
    ushort_t* dBl1 = &sBl[(64 + srow) * 32 + skc];
    for (int k0 = 0; k0 < K; k0 += 32) {
        __syncthreads();
        async16(pAh0, dA0);  async16(pAh1, dA1);
        async16(pAl0, dAl0); async16(pAl1, dAl1);
        async16(pBh0, dB0);  async16(pBh1, dB1);
        async16(pBl0, dBl0); async16(pBl1, dBl1);
        pAh0 += 32; pAh1 += 32; pAl0 += 32; pAl1 += 32;
        pBh0 += 32; pBh1 += 32; pBl0 += 32; pBl1 += 32;
        __syncthreads();
        short8 ahf[4], alf[4], bhf[4], blf[4];
        for (int i = 0; i < 4; ++i) {
            int ro = (wm + i * 16 + fr) * 32 + fk;
            ahf[i] = *(const short8*)&sAh[ro];
            alf[i] = *(const short8*)&sAl[ro];
        }
        for (int j = 0; j < 4; ++j) {
            int ro = (wn + j * 16 + fr) * 32 + fk;
            bhf[j] = *(const short8*)&sBh[ro];
            blf[j] = *(const short8*)&sBl[ro];
        }
        for (int i = 0; i < 4; ++i)
            for (int j = 0; j < 4; ++j) {
                acc[i][j] = mfma_bf16(ahf[i], bhf[j], acc[i][j]);
                acc[i][j] = mfma_bf16(ahf[i], blf[j], acc[i][j]);
                acc[i][j] = mfma_bf16(alf[i], bhf[j], acc[i][j]);
            }
    }
    const int cr = (lane >> 4) * 4, cc = lane & 15;
    for (int i = 0; i < 4; ++i)
        for (int j = 0; j < 4; ++j) {
            int row = bm + wm + i * 16 + cr;
            int col = bn + wn + j * 16 + cc;
            if (col < N)
                for (int r = 0; r < 4; ++r)
                    C[(size_t)(row + r) * N + col] = acc[i][j][r];
        }
}

// ---------------- RMSNorm (strided in, fp32 out) ----------------
__global__ __launch_bounds__(256) void rms_kernel(const float* __restrict__ in, float* __restrict__ out,
                                                  const float* __restrict__ w, int C, int ldin, int ldout) {
    const int row = blockIdx.x;
    const float* xr = in + (size_t)row * ldin;
    float* yr = out + (size_t)row * ldout;
    float ss = 0.f;
    for (int c = threadIdx.x; c < C; c += 256) { float v = xr[c]; ss += v * v; }
    for (int o = 32; o; o >>= 1) ss += __shfl_down(ss, o, 64);
    __shared__ float red[4];
    const int wave = threadIdx.x >> 6, lane = threadIdx.x & 63;
    if (lane == 0) red[wave] = ss;
    __syncthreads();
    const float tot = red[0] + red[1] + red[2] + red[3];
    const float scale = rsqrtf(tot / (float)C + 1e-6f);
    for (int c = threadIdx.x; c < C; c += 256) yr[c] = w[c] * (xr[c] * scale);
}

// ---------------- RMSNorm (strided in, bf16 hi/lo packed out) ----------------
__global__ __launch_bounds__(256) void rms_split_kernel(const float* __restrict__ in, ushort_t* __restrict__ hi,
                                                        ushort_t* __restrict__ lo, const float* __restrict__ w,
                                                        int C, int ldin) {
    const int row = blockIdx.x;
    const float* xr = in + (size_t)row * ldin;
    float ss = 0.f;
    for (int c = threadIdx.x; c < C; c += 256) { float v = xr[c]; ss += v * v; }
    for (int o = 32; o; o >>= 1) ss += __shfl_down(ss, o, 64);
    __shared__ float red[4];
    const int wave = threadIdx.x >> 6, lane = threadIdx.x & 63;
    if (lane == 0) red[wave] = ss;
    __syncthreads();
    const float tot = red[0] + red[1] + red[2] + red[3];
    const float scale = rsqrtf(tot / (float)C + 1e-6f);
    for (int c = threadIdx.x; c < C; c += 256) {
        float v = w[c] * (xr[c] * scale);
        unsigned short h = f2bf(v);
        hi[(size_t)row * C + c] = h;
        lo[(size_t)row * C + c] = f2bf(v - bf2f(h));
    }
}

// ---------------- LayerNorm row length 128 (strided, in place) ----------------
__global__ __launch_bounds__(128) void ln_kernel(float* __restrict__ x, const float* __restrict__ w,
                                                 const float* __restrict__ b, int ld) {
    const int row = blockIdx.x;
    float* xr = x + (size_t)row * ld;
    const int tid = threadIdx.x;
    float v = xr[tid];
    float sm = v;
    for (int o = 32; o; o >>= 1) sm += __shfl_down(sm, o, 64);
    __shared__ float red[2];
    if ((tid & 63) == 0) red[tid >> 6] = sm;
    __syncthreads();
    const float mu = (red[0] + red[1]) * (1.f / 128.f);
    __syncthreads();
    float d = v - mu;
    float sv = d * d;
    for (int o = 32; o; o >>= 1) sv += __shfl_down(sv, o, 64);
    if ((tid & 63) == 0) red[tid >> 6] = sv;
    __syncthreads();
    const float var = (red[0] + red[1]) * (1.f / 128.f);
    const float rs = rsqrtf(var + 1e-6f);
    xr[tid] = (v - mu) * rs * w[tid] + b[tid];
}

// ---------------- RoPE interleaved: p = X + s*ld + h*hs + off ----------------
__global__ __launch_bounds__(256) void rope_inter_kernel(float* __restrict__ X, const float* __restrict__ ct,
                                                         const float* __restrict__ st, int H, int hs, int off,
                                                         int ld) {
    int idx = blockIdx.x * 256 + threadIdx.x;
    int k = idx & 31;
    int h = (idx >> 5) % H;
    int s = idx / (32 * H);
    if (s >= S) return;
    float c = ct[s * 32 + k], sn = st[s * 32 + k];
    float* p = X + (size_t)s * ld + h * hs + off;
    float x1 = p[2 * k], x2 = p[2 * k + 1];
    p[2 * k]     = x1 * c - x2 * sn;
    p[2 * k + 1] = x1 * sn + x2 * c;
}

// ---------------- RoPE half: p = X + s*ld + h*hs ----------------
__global__ __launch_bounds__(256) void rope_half_kernel(float* __restrict__ X, const float* __restrict__ ct,
                                                        const float* __restrict__ st, int H, int hs, int ld) {
    int idx = blockIdx.x * 256 + threadIdx.x;
    int k = idx & 31;
    int h = (idx >> 5) % H;
    int s = idx / (32 * H);
    if (s >= S) return;
    float c = ct[s * 32 + k], sn = st[s * 32 + k];
    float* p = X + (size_t)s * ld + h * hs;
    float x1 = p[k], x2 = p[32 + k];
    p[k]      = x1 * c - x2 * sn;
    p[32 + k] = x1 * sn + x2 * c;
}

// ---------------- Hadamard rotate: in strided (s*lds + h*128), out packed r*128 ----------------
__global__ __launch_bounds__(128) void rotate_kernel(const float* __restrict__ in, int lds, int H,
                                                     bf16* __restrict__ out) {
    __shared__ float xs[128];
    const int r = blockIdx.x, j = threadIdx.x;
    const int s = r / H, h = r - s * H;
    float v = in[(size_t)s * lds + h * 128 + j];
    xs[j] = __bfloat162float(__float2bfloat16(v));
    __syncthreads();
    float acc = 0.f;
    for (int d = 0; d < 128; ++d) {
        float xv = xs[d];
        acc += (__popc(d & j) & 1) ? -xv : xv;
    }
    float t = __bfloat162float(__float2bfloat16(acc)) * 0.08838834764831845f;
    out[(size_t)r * 128 + j] = __float2bfloat16(t);
}

// ---------------- wq scale: iw read from strided xp slice; 0.25 folded here ----------------
__global__ __launch_bounds__(256) void wq_kernel(const float* __restrict__ iwb, bf16* __restrict__ iqr) {
    int idx = blockIdx.x * 256 + threadIdx.x;
    int s = idx >> 11, h = (idx >> 7) & 15;
    float a = 0.25f * iwb[(size_t)s * XPLD + h];
    float v = __bfloat162float(iqr[idx]);
    float t = (a * v) * 0.08838834764831845f;
    iqr[idx] = __float2bfloat16(t);
}

// ---------------- index score via bf16 MFMA ----------------
__global__ __launch_bounds__(256) void iscore_mfma(const bf16* __restrict__ wq, const bf16* __restrict__ ik,
                                                   float* __restrict__ out) {
    if (blockIdx.x > blockIdx.y) return;
    __shared__ unsigned short As[128 * 32], Bs[128 * 32];
    const int bs = blockIdx.y * 128, bt = blockIdx.x * 128;
    const int tid = threadIdx.x, w = tid >> 6, lane = tid & 63;
    const int wm = (w >> 1) * 64, wn = (w & 1) * 64;
    const int fr = lane & 15, fk = (lane >> 4) * 8;
    const int srow = lane >> 2, skc = (lane & 3) * 8;
    f32x4 sum[4][4];
    for (int i = 0; i < 4; ++i)
        for (int j = 0; j < 4; ++j) sum[i][j] = f32x4{0.f, 0.f, 0.f, 0.f};
    for (int h = 0; h < 16; ++h) {
        f32x4 acc[4][4];
        for (int i = 0; i < 4; ++i)
            for (int j = 0; j < 4; ++j) acc[i][j] = f32x4{0.f, 0.f, 0.f, 0.f};
        for (int k0 = 0; k0 < 128; k0 += 32) {
            __syncthreads();
            for (int i = 0; i < 2; ++i) {
                int seg = i * 4 + w;
                async16(wq + (size_t)(bs + seg * 16 + srow) * 2048 + h * 128 + k0 + skc, &As[seg * 512]);
                async16(ik + (size_t)(bt + seg * 16 + srow) * 128 + k0 + skc, &Bs[seg * 512]);
            }
            __syncthreads();
            short8 af[4], bff[4];
            for (int i = 0; i < 4; ++i) af[i]  = *(const short8*)&As[(wm + i * 16 + fr) * 32 + fk];
            for (int j = 0; j < 4; ++j) bff[j] = *(const short8*)&Bs[(wn + j * 16 + fr) * 32 + fk];
            for (int i = 0; i < 4; ++i)
                for (int j = 0; j < 4; ++j)
                    acc[i][j] = mfma_bf16(af[i], bff[j], acc[i][j]);
        }
        for (int i = 0; i < 4; ++i)
            for (int j = 0; j < 4; ++j)
                for (int r = 0; r < 4; ++r)
                    sum[i][j][r] += fmaxf(acc[i][j][r], 0.f);
    }
    const int cr = (lane >> 4) * 4, cc = lane & 15;
    for (int i = 0; i < 4; ++i)
        for (int j = 0; j < 4; ++j)
            for (int r = 0; r < 4; ++r)
                out[(size_t)(bs + wm + i * 16 + cr + r) * 2048 + bt + wn + j * 16 + cc] = sum[i][j][r];
}

// ---------------- top-k ----------------
__global__ __launch_bounds__(256) void topk_kernel(const float* __restrict__ isc, int* __restrict__ tk) {
    __shared__ unsigned long long keys[2048];
    const int s = blockIdx.x;
    const float* row = isc + (size_t)s * 2048;
    for (int t = threadIdx.x; t < 2048; t += 256) {
        unsigned long long kk = 0ull;
        if (t <= s) {
            unsigned int vb = __float_as_uint(row[t]);
            kk = ((unsigned long long)vb << 32) | (unsigned int)(2048 - t);
        }
        keys[t] = kk;
    }
    __syncthreads();
    for (int k = 2; k <= 2048; k <<= 1) {
        for (int j = k >> 1; j > 0; j >>= 1) {
            for (int t = threadIdx.x; t < 2048; t += 256) {
                int l = t ^ j;
                if (l > t) {
                    bool up = ((t & k) == 0);
                    unsigned long long a = keys[t], b = keys[l];
                    bool sw = up ? (a < b) : (a > b);
                    if (sw) { keys[t] = b; keys[l] = a; }
                }
            }
            __syncthreads();
        }
    }
    const int cnt = min(1024, s + 1);
    for (int i = threadIdx.x; i < 1024; i += 256) {
        int t = (i < cnt) ? (2048 - (int)(keys[i] & 0xFFFFFFFFull)) : -1;
        tk[(size_t)s * 1024 + i] = t;
    }
}

// ---------------- transpose kv_b head-1 part ----------------
__global__ __launch_bounds__(256) void w1t_kernel(const float* __restrict__ kv_b, float* __restrict__ w1t) {
    __shared__ float ts[64][65];
    const int cb = blockIdx.x * 64, db = blockIdx.y * 64, h = blockIdx.z;
    const int t = threadIdx.x;
    for (int it = 0; it < 16; ++it) {
        int idx = it * 256 + t;
        int rr = idx >> 6, cc = idx & 63;
        ts[rr][cc] = kv_b[(size_t)(h * 256 + db + rr) * 512 + cb + cc];
    }
    __syncthreads();
    for (int it = 0; it < 16; ++it) {
        int idx = it * 256 + t;
        int rr = idx >> 6, cc = idx & 63;
        w1t[(size_t)h * 65536 + (size_t)(cb + rr) * 128 + db + cc] = ts[cc][rr];
    }
}

// ---------------- kv split: hi/lo rows of 576 for score; packed u32 {hi,lo} V rows for pv ----------------
__global__ __launch_bounds__(576) void kvsplit_kernel(const float* __restrict__ kv, const float* __restrict__ kpe,
                                                      ushort_t* __restrict__ kvh, ushort_t* __restrict__ kvl,
                                                      unsigned int* __restrict__ kvi) {
    const int t = blockIdx.x, c = threadIdx.x;
    float v = (c < 512) ? kv[(size_t)t * 512 + c] : kpe[(size_t)t * XPLD + c];
    unsigned short hi = f2bf(v);
    unsigned short lo = f2bf(v - bf2f(hi));
    kvh[(size_t)t * 576 + c] = hi;
    kvl[(size_t)t * 576 + c] = lo;
    if (c < 512) kvi[(size_t)t * 512 + c] = (unsigned int)hi | ((unsigned int)lo << 16);
}

// ---------------- qabs via bf16x3 MFMA (q strided from packed qib) ----------------
__global__ __launch_bounds__(256) void qabs_mfma(const float* __restrict__ q, const float* __restrict__ w1t,
                                                 ushort_t* __restrict__ qah, ushort_t* __restrict__ qal) {
    __shared__ unsigned short Ah[128 * PADK], Al[128 * PADK], Bh[128 * PADK], Bl[128 * PADK];
    const int tid = threadIdx.x;
    const int bn = blockIdx.x * 128, bm = blockIdx.y * 128, h = blockIdx.z;
    const int w = tid >> 6, lane = tid & 63;
    const int wm = (w >> 1) * 64, wn = (w & 1) * 64;
    const int fr = lane & 15, fk = (lane >> 4) * 8;
    f32x4 acc[4][4];
    for (int i = 0; i < 4; ++i)
        for (int j = 0; j < 4; ++j) acc[i][j] = f32x4{0.f, 0.f, 0.f, 0.f};
    for (int k0 = 0; k0 < 128; k0 += 32) {
        __syncthreads();
        for (int it = 0; it < 4; ++it) {
            int f = it * 256 + tid;
            int row = f >> 3, kc = (f & 7) * 4;
            float4 av = *(const float4*)(q + (size_t)(bm + row) * QLD + h * QK_HD + k0 + kc);
            float4 bv = *(const float4*)(w1t + (size_t)h * 65536 + (size_t)(bn + row) * 128 + k0 + kc);
            ushort4 ahi, alo, bhi, blo;
            ahi.x = f2bf(av.x); alo.x = f2bf(av.x - bf2f(ahi.x));
            ahi.y = f2bf(av.y); alo.y = f2bf(av.y - bf2f(ahi.y));
            ahi.z = f2bf(av.z); alo.z = f2bf(av.z - bf2f(ahi.z));
            ahi.w = f2bf(av.w); alo.w = f2bf(av.w - bf2f(ahi.w));
            bhi.x = f2bf(bv.x); blo.x = f2bf(bv.x - bf2f(bhi.x));
            bhi.y = f2bf(bv.y); blo.y = f2bf(bv.y - bf2f(bhi.y));
            bhi.z = f2bf(bv.z); blo.z = f2bf(bv.z - bf2f(bhi.z));
            bhi.w = f2bf(bv.w); blo.w = f2bf(bv.w - bf2f(bhi.w));
            *(ushort4*)&Ah[row * PADK + kc] = ahi;
            *(ushort4*)&Al[row * PADK + kc] = alo;
            *(ushort4*)&Bh[row * PADK + kc] = bhi;
            *(ushort4*)&Bl[row * PADK + kc] = blo;
        }
        __syncthreads();
        short8 ahf[4], alf[4], bhf[4], blf[4];
        for (int i = 0; i < 4; ++i) {
            int ro = (wm + i * 16 + fr) * PADK + fk;
            ahf[i] = *(const short8*)&Ah[ro];
            alf[i] = *(const short8*)&Al[ro];
        }
        for (int j = 0; j < 4; ++j) {
            int ro = (wn + j * 16 + fr) * PADK + fk;
            bhf[j] = *(const short8*)&Bh[ro];
            blf[j] = *(const short8*)&Bl[ro];
        }
        for (int i = 0; i < 4; ++i)
            for (int j = 0; j < 4; ++j) {
                acc[i][j] = mfma_bf16(ahf[i], bhf[j], acc[i][j]);
                acc[i][j] = mfma_bf16(ahf[i], blf[j], acc[i][j]);
                acc[i][j] = mfma_bf16(alf[i], bhf[j], acc[i][j]);
            }
    }
    const int cr = (lane >> 4) * 4, cc = lane & 15;
    for (int i = 0; i < 4; ++i)
        for (int j = 0; j < 4; ++j)
            for (int r = 0; r < 4; ++r) {
                int srow = bm + wm + i * 16 + cr + r;
                int col = bn + wn + j * 16 + cc;
                float f = acc[i][j][r] * SM_SCALE;
                size_t addr = ((size_t)srow * 16 + h) * 576 + col;
                unsigned short hi = f2bf(f);
                qah[addr] = hi;
                qal[addr] = f2bf(f - bf2f(hi));
            }
}

// ---------------- qpe split (q strided from packed qib) ----------------
__global__ __launch_bounds__(256) void qpe_split(const float* __restrict__ q, ushort_t* __restrict__ qah,
                                                 ushort_t* __restrict__ qal) {
    int idx = blockIdx.x * 256 + threadIdx.x;
    int r = idx & 63, h = (idx >> 6) & 15, s = idx >> 10;
    float f = q[(size_t)s * QLD + h * QK_HD + 128 + r] * SM_SCALE;
    size_t addr = ((size_t)s * 16 + h) * 576 + 512 + r;
    unsigned short hi = f2bf(f);
    qah[addr] = hi;
    qal[addr] = f2bf(f - bf2f(hi));
}

// ---------------- attn_score via MFMA bf16x3 — 2-phase pipelined, XCD-swizzled pass-split grid ----------------
// 1D grid 2048. T1 swizzle: dispatcher round-robins blocks over 8 XCDs, so logical work id
// w = (bid&7)*256 + (bid>>3) gives each XCD 256 CONSECUTIVE (query,pass) slots -> overlapping
// top-k key rows stay hot in that XCD's 4MB L2 (round-4: 143MB L3/HBM re-fetch per dispatch).
__global__ __launch_bounds__(512) void attn_score_mfma(const ushort_t* __restrict__ qah,
                                                       const ushort_t* __restrict__ qal,
                                                       const ushort_t* __restrict__ kvh,
                                                       const ushort_t* __restrict__ kvl,
                                                       const int* __restrict__ tk,
                                                       float* __restrict__ scb, int s0) {
    const int bid = blockIdx.x;
    const int wid = (bid & 7) * 256 + (bid >> 3);   // bijective (2048 % 8 == 0)
    const int sl = wid & 511, pass = wid >> 9;
    const int s = s0 + sl;
    const int tid = threadIdx.x, w = tid >> 6, lane = tid & 63;
    const int cnt = min(1024, s + 1);
    if (pass * 256 >= cnt) {  // whole pass masked: write NEG and exit (no gather)
        for (int i = tid; i < 4096; i += 512) {
            int head = i >> 8, key = i & 255;
            scb[((size_t)sl * 16 + head) * 1024 + pass * 256 + key] = -1e30f;
        }
        return;
    }
    __shared__ int tks[256];
    __shared__ __align__(16) ushort_t kh[2][8192], kl[2][8192];
    if (tid < 256) {
        int t = tk[(size_t)s * 1024 + pass * 256 + tid];
        tks[tid] = t < 0 ? 0 : t;
    }
    __syncthreads();
    const int fr = lane & 15, g = lane >> 4;
    const size_t abase = ((size_t)s * 16 + fr) * 576 + g * 8;
    const int R0 = tid >> 2;
    const int sw = (tid & 3) ^ ((R0 >> 1) & 3);
    const size_t t0 = (size_t)tks[R0], t1 = (size_t)tks[R0 + 128];
    const ushort_t* gh0 = kvh + t0 * 576 + sw * 8;
    const ushort_t* gh1 = kvh + t1 * 576 + sw * 8;
    const ushort_t* gl0 = kvl + t0 * 576 + sw * 8;
    const ushort_t* gl1 = kvl + t1 * 576 + sw * 8;
    const int ro_a = (w * 32 + fr) * 32 + ((g ^ ((fr >> 1) & 3)) << 3);
    async16(gh0, &kh[0][w * 512]);
    async16(gh1, &kh[0][4096 + w * 512]);
    async16(gl0, &kl[0][w * 512]);
    async16(gl1, &kl[0][4096 + w * 512]);
    short8 qh = *(const short8*)(qah + abase);
    short8 ql = *(const short8*)(qal + abase);
    f32x4 acc0 = {0.f, 0.f, 0.f, 0.f}, acc1 = {0.f, 0.f, 0.f, 0.f};
    int cur = 0;
    __syncthreads();
    for (int ch = 0; ch < 18; ++ch) {
        if (ch < 17) {
            int off = (ch + 1) * 32;
            async16(gh0 + off, &kh[cur ^ 1][w * 512]);
            async16(gh1 + off, &kh[cur ^ 1][4096 + w * 512]);
            async16(gl0 + off, &kl[cur ^ 1][w * 512]);
            async16(gl1 + off, &kl[cur ^ 1][4096 + w * 512]);
        }
        short8 qhc = qh, qlc = ql;
        if (ch < 17) {
            qh = *(const short8*)(qah + abase + (ch + 1) * 32);
            ql = *(const short8*)(qal + abase + (ch + 1) * 32);
        }
        short8 bh0 = *(const short8*)&kh[cur][ro_a];
        short8 bl0 = *(const short8*)&kl[cur][ro_a];
        short8 bh1 = *(const short8*)&kh[cur][ro_a + 512];
        short8 bl1 = *(const short8*)&kl[cur][ro_a + 512];
        acc0 = mfma_bf16(qhc, bh0, acc0);
        acc0 = mfma_bf16(qhc, bl0, acc0);
        acc0 = mfma_bf16(qlc, bh0, acc0);
        acc1 = mfma_bf16(qhc, bh1, acc1);
        acc1 = mfma_bf16(qhc, bl1, acc1);
        acc1 = mfma_bf16(qlc, bh1, acc1);
        __syncthreads();
        cur ^= 1;
    }
    const int cr = (lane >> 4) * 4, cc = lane & 15;
    for (int r = 0; r < 4; ++r) {
        int head = cr + r;
        int key0 = pass * 256 + w * 32 + cc;
        int key1 = key0 + 16;
        scb[((size_t)sl * 16 + head) * 1024 + key0] = (key0 < cnt) ? acc0[r] : -1e30f;
        scb[((size_t)sl * 16 + head) * 1024 + key1] = (key1 < cnt) ? acc1[r] : -1e30f;
    }
}

// ---------------- softmax -> p as bf16 hi/lo ----------------
__global__ __launch_bounds__(256) void softmax_pb(const float* __restrict__ scb,
                                                  ushort_t* __restrict__ pbh, ushort_t* __restrict__ pbl) {
    const size_t row = blockIdx.x;
    const float* src = scb + row * 1024;
    const int tid = threadIdx.x, wave = tid >> 6, lane = tid & 63;
    __shared__ float red[4];
    float v[4];
    float m = -INFINITY;
    for (int i = 0; i < 4; ++i) { v[i] = src[tid + 256 * i]; m = fmaxf(m, v[i]); }
    for (int o = 32; o; o >>= 1) m = fmaxf(m, __shfl_down(m, o, 64));
    if (lane == 0) red[wave] = m;
    __syncthreads();
    m = fmaxf(fmaxf(red[0], red[1]), fmaxf(red[2], red[3]));
    __syncthreads();
    float e[4], l = 0.f;
    for (int i = 0; i < 4; ++i) { e[i] = __expf(v[i] - m); l += e[i]; }
    for (int o = 32; o; o >>= 1) l += __shfl_down(l, o, 64);
    if (lane == 0) red[wave] = l;
    __syncthreads();
    const float il = 1.f / (red[0] + red[1] + red[2] + red[3]);
    for (int i = 0; i < 4; ++i) {
        float p = e[i] * il;
        unsigned short hi = f2bf(p);
        pbh[row * 1024 + tid + 256 * i] = hi;
        pbl[row * 1024 + tid + 256 * i] = f2bf(p - bf2f(hi));
    }
}

// ---------------- attn_pv via MFMA bf16x3 — packed {hi,lo} V, NAMED-reg prefetch, XCD-swizzled grid ----
#define PV_GATHER(KC)                                                                    \
    g0 = *(const uint4*)(kvi + (size_t)tks[(KC) * 32 + r0     ] * 512 + gp4);            \
    g1 = *(const uint4*)(kvi + (size_t)tks[(KC) * 32 + r0 + 4 ] * 512 + gp4);            \
    g2 = *(const uint4*)(kvi + (size_t)tks[(KC) * 32 + r0 + 8 ] * 512 + gp4);            \
    g3 = *(const uint4*)(kvi + (size_t)tks[(KC) * 32 + r0 + 12] * 512 + gp4);            \
    g4 = *(const uint4*)(kvi + (size_t)tks[(KC) * 32 + r0 + 16] * 512 + gp4);            \
    g5 = *(const uint4*)(kvi + (size_t)tks[(KC) * 32 + r0 + 20] * 512 + gp4);            \
    g6 = *(const uint4*)(kvi + (size_t)tks[(KC) * 32 + r0 + 24] * 512 + gp4);            \
    g7 = *(const uint4*)(kvi + (size_t)tks[(KC) * 32 + r0 + 28] * 512 + gp4);
#define PV_STORE()                                                                       \
    *(uint4*)&vt[(r0     ) * 512 + ((gp ^ 0) << 2)] = g0;                                \
    *(uint4*)&vt[(r0 + 4 ) * 512 + ((gp ^ 0) << 2)] = g1;                                \
    *(uint4*)&vt[(r0 + 8 ) * 512 + ((gp ^ 2) << 2)] = g2;                                \
    *(uint4*)&vt[(r0 + 12) * 512 + ((gp ^ 2) << 2)] = g3;                                \
    *(uint4*)&vt[(r0 + 16) * 512 + ((gp ^ 4) << 2)] = g4;                                \
    *(uint4*)&vt[(r0 + 20) * 512 + ((gp ^ 4) << 2)] = g5;                                \
    *(uint4*)&vt[(r0 + 24) * 512 + ((gp ^ 6) << 2)] = g6;                                \
    *(uint4*)&vt[(r0 + 28) * 512 + ((gp ^ 6) << 2)] = g7;
__global__ __launch_bounds__(512) void attn_pv_mfma(const ushort_t* __restrict__ pbh,
                                                    const ushort_t* __restrict__ pbl,
                                                    const unsigned int* __restrict__ kvi,
                                                    const int* __restrict__ tk,
                                                    ushort_t* __restrict__ o1h, ushort_t* __restrict__ o1l,
                                                    int s0) {
    const int bid = blockIdx.x;
    const int sl = (bid & 7) * 64 + (bid >> 3);     // T1: 64 consecutive queries per XCD (512 % 8 == 0)
    const int s = s0 + sl;
    const int tid = threadIdx.x, w = tid >> 6, lane = tid & 63;
    __shared__ int tks[1024];
    __shared__ unsigned int vt[32 * 512];   // 64 KiB
    for (int j = tid; j < 1024; j += 512) {
        int t = tk[(size_t)s * 1024 + j];
        tks[j] = t < 0 ? 0 : t;
    }
    const int fr = lane & 15, g = lane >> 4, fko = g * 8;
    const int r0 = tid >> 7;        // 0..3
    const int gp = tid & 127;       // 16B granule column (4 u32)
    const int gp4 = gp * 4;
    f32x4 acc[4];
    for (int i = 0; i < 4; ++i) acc[i] = f32x4{0.f, 0.f, 0.f, 0.f};
    const size_t pbase = ((size_t)sl * 16 + fr) * 1024 + fko;
    uint4 g0, g1, g2, g3, g4, g5, g6, g7;
    __syncthreads();                // tks ready
    PV_GATHER(0)
    PV_STORE()
    __syncthreads();                // vt chunk 0 ready
    for (int kc = 0; kc < 32; ++kc) {
        if (kc < 31) {              // prefetch next chunk into named regs (coalesced 1KB per wave)
            PV_GATHER(kc + 1)
        }
        short8 ph = *(const short8*)(pbh + pbase + kc * 32);
        short8 pl = *(const short8*)(pbl + pbase + kc * 32);
        #pragma unroll
        for (int sub = 0; sub < 4; ++sub) {
            const int cb = (w * 64 + sub * 16 + fr) ^ (g << 3);
            short8 bh, bl;
            #pragma unroll
            for (int jj = 0; jj < 8; ++jj) {
                const unsigned int v = vt[(fko + jj) * 512 + cb];
                bh[jj] = (short)(v & 0xffffu);
                bl[jj] = (short)(v >> 16);
            }
            acc[sub] = mfma_bf16(ph, bh, acc[sub]);
            acc[sub] = mfma_bf16(pl, bh, acc[sub]);
            acc[sub] = mfma_bf16(ph, bl, acc[sub]);
        }
        __syncthreads();            // all waves done reading vt
        if (kc < 31) {
            PV_STORE()
            __syncthreads();        // vt next chunk ready
        }
    }
    const int cr = (lane >> 4) * 4, cc = lane & 15;
    for (int sub = 0; sub < 4; ++sub)
        for (int r = 0; r < 4; ++r) {
            int head = cr + r, c = w * 64 + sub * 16 + cc;
            float f = acc[sub][r];
            unsigned short hv = f2bf(f);
            size_t addr = ((size_t)sl * 16 + head) * 512 + c;
            o1h[addr] = hv;
            o1l[addr] = f2bf(f - bf2f(hv));
        }
}

// ---------------- outproj via pre-split bf16x3 MFMA (gemm3_lds structure) ----------------
__global__ __launch_bounds__(256) void outproj_mfma(const ushort_t* __restrict__ o1h,
                                                    const ushort_t* __restrict__ o1l,
                                                    const ushort_t* __restrict__ w2h,
                                                    const ushort_t* __restrict__ w2l,
                                                    ushort_t* __restrict__ o2h, ushort_t* __restrict__ o2l,
                                                    int s0) {
    __shared__ ushort_t sAh[128 * 32], sAl[128 * 32], sBh[128 * 32], sBl[128 * 32];
    const int tid = threadIdx.x;
    const int bm = blockIdx.x * 128, h = blockIdx.y;
    const int w = tid >> 6, lane = tid & 63;
    const int wm = (w >> 1) * 64, wn = (w & 1) * 64;
    const int fr = lane & 15, fk = (lane >> 4) * 8;
    const int srow = tid >> 2, skc = (tid & 3) * 8;
    f32x4 acc[4][4];
    for (int i = 0; i < 4; ++i)
        for (int j = 0; j < 4; ++j) acc[i][j] = f32x4{0.f, 0.f, 0.f, 0.f};
    const ushort_t* pAh0 = o1h + ((size_t)(bm + srow) * 16 + h) * 512 + skc;
    const ushort_t* pAh1 = o1h + ((size_t)(bm + 64 + srow) * 16 + h) * 512 + skc;
    const ushort_t* pAl0 = o1l + ((size_t)(bm + srow) * 16 + h) * 512 + skc;
    const ushort_t* pAl1 = o1l + ((size_t)(bm + 64 + srow) * 16 + h) * 512 + skc;
    const ushort_t* pBh0 = w2h + ((size_t)(h * 128 + srow)) * 512 + skc;
    const ushort_t* pBh1 = w2h + ((size_t)(h * 128 + 64 + srow)) * 512 + skc;
    const ushort_t* pBl0 = w2l + ((size_t)(h * 128 + srow)) * 512 + skc;
    const ushort_t* pBl1 = w2l + ((size_t)(h * 128 + 64 + srow)) * 512 + skc;
    ushort_t* dA0 = &sAh[srow * 32 + skc];
    ushort_t* dA1 = &sAh[(64 + srow) * 32 + skc];
    ushort_t* dAl0 = &sAl[srow * 32 + skc];
    ushort_t* dAl1 = &sAl[(64 + srow) * 32 + skc];
    ushort_t* dB0 = &sBh[srow * 32 + skc];
    ushort_t* dB1 = &sBh[(64 + srow) * 32 + skc];
    ushort_t* dBl0 = &sBl[srow * 32 + skc];
    ushort_t* dBl1 = &sBl[(64 + srow) * 32 + skc];
    for (int k0 = 0; k0 < 512; k0 += 32) {
        __syncthreads();
        async16(pAh0, dA0);  async16(pAh1, dA1);
        async16(pAl0, dAl0); async16(pAl1, dAl1);
        async16(pBh0, dB0);  async16(pBh1, dB1);
        async16(pBl0, dBl0); async16(pBl1, dBl1);
        pAh0 += 32; pAh1 += 32; pAl0 += 32; pAl1 += 32;
        pBh0 += 32; pBh1 += 32; pBl0 += 32; pBl1 += 32;
        __syncthreads();
        short8 ahf[4], alf[4], bhf[4], blf[4];
        for (int i = 0; i < 4; ++i) {
            int ro = (wm + i * 16 + fr) * 32 + fk;
            ahf[i] = *(const short8*)&sAh[ro];
            alf[i] = *(const short8*)&sAl[ro];
        }
        for (int j = 0; j < 4; ++j) {
            int ro = (wn + j * 16 + fr) * 32 + fk;
            bhf[j] = *(const short8*)&sBh[ro];
            blf[j] = *(const short8*)&sBl[ro];
        }
        for (int i = 0; i < 4; ++i)
            for (int j = 0; j < 4; ++j) {
                acc[i][j] = mfma_bf16(ahf[i], bhf[j], acc[i][j]);
                acc[i][j] = mfma_bf16(ahf[i], blf[j], acc[i][j]);
                acc[i][j] = mfma_bf16(alf[i], bhf[j], acc[i][j]);
            }
    }
    const int cr = (lane >> 4) * 4, cc = lane & 15;
    for (int i = 0; i < 4; ++i)
        for (int j = 0; j < 4; ++j)
            for (int r = 0; r < 4; ++r) {
                int srow2 = s0 + bm + wm + i * 16 + cr + r;
                int col = wn + j * 16 + cc;
                size_t addr = (size_t)srow2 * 2048 + h * 128 + col;
                float f = acc[i][j][r];
                unsigned short hv = f2bf(f);
                o2h[addr] = hv;
                o2l[addr] = f2bf(f - bf2f(hv));
            }
}

extern "C" void kernel_launch(void* const* d_in, const int* in_sizes, int n_in,
                              void* d_out, int out_size, void* d_ws, size_t ws_size,
                              hipStream_t stream) {
    const float* x         = (const float*)d_in[0];
    const float* fcos      = (const float*)d_in[2];
    const float* fsin      = (const float*)d_in[3];
    const float* q_a_proj  = (const float*)d_in[5];
    const float* q_a_ln_w  = (const float*)d_in[6];
    const float* q_b_proj  = (const float*)d_in[7];
    const float* kv_a_proj = (const float*)d_in[8];
    const float* kv_a_ln_w = (const float*)d_in[9];
    const float* kv_b      = (const float*)d_in[10];
    const float* o_proj    = (const float*)d_in[11];
    const float* idx_wq_b  = (const float*)d_in[12];
    const float* idx_wk    = (const float*)d_in[13];
    const float* iknw      = (const float*)d_in[14];
    const float* iknb      = (const float*)d_in[15];
    const float* idx_wp    = (const float*)d_in[16];
    float* out = (float*)d_out;

    char* ws = (char*)d_ws;
    size_t off = 0;
    auto alloc = [&](size_t bytes) {
        char* p = ws + off;
        off += (bytes + 255) & ~(size_t)255;
        return p;
    };
    // ---- Region A (mostly dead by attention-chunk phase; chunk scratch overlays first 80 MiB) ----
    float* xp  = (float*)alloc((size_t)S * XPLD * 4);     // 17.6 MB
    ushort_t* qrh = (ushort_t*)alloc((size_t)S * Q_LORA * 2);  // 6 MB
    ushort_t* qrl = (ushort_t*)alloc((size_t)S * Q_LORA * 2);  // 6 MB
    float* qib = (float*)alloc((size_t)S * QLD * 4);      // 40 MB: [q 3072 | iqf 2048]
    char* RAt  = alloc(31457280);                         // 30 MiB overlay region (abs 69.6..99.6 MiB)
    float* isc = (float*)RAt;                             // 16.8 MB (dead after topk)
    bf16* iqr  = (bf16*)(RAt + 16777216);                 // 8.4 MB (dead after iscore)
    bf16* ikr  = (bf16*)(RAt + 16777216 + 8388608);       // 0.5 MB (dead after iscore)
    ushort_t* xh = (ushort_t*)RAt;                        // x split (dead after GEMM1)
    ushort_t* xl = xh + (size_t)S * DIM;
    ushort_t* wq2h = (ushort_t*)RAt;                      // q_b|idx_wq_b split (written after GEMM1)
    ushort_t* wq2l = wq2h + (size_t)5120 * Q_LORA;
    float* w1t = (float*)RAt;                             // 4.2 MB (written after topk reads isc)
    ushort_t* wpackh = (ushort_t*)qib;                    // x-proj B split (dead before qib written)
    ushort_t* wpackl = wpackh + (size_t)XPLD_PAD * DIM;
    // RAt tail (abs 91.6..99.6 MiB, beyond the 80 MiB chunk scratch): survives chunk phase.
    char* kvtail = RAt + (size_t)22 * 1024 * 1024;
    unsigned int* kvi = (unsigned int*)kvtail;                       // 4 MiB packed {hi,lo} V
    ushort_t* w2h = (ushort_t*)(kvtail + (size_t)4 * 1024 * 1024);   // 2 MiB
    ushort_t* w2l = w2h + (size_t)16 * 128 * 512;                    // 2 MiB
    // pad region A to cover chunk scratch (scb 32MiB + pbh 16 + pbl 16 + o1h/l 16 = 80 MiB)
    const size_t CHUNK_BYTES = (size_t)SCHUNK * 16 * 1024 * 4 + (size_t)SCHUNK * 16 * 1024 * 2 * 2
                             + (size_t)SCHUNK * 16 * 512 * 4;
    if (off < CHUNK_BYTES) off = (CHUNK_BYTES + 255) & ~(size_t)255;
    // ---- Persistent ----
    int* tk        = (int*)alloc((size_t)S * 1024 * 4);
    float* kv      = (float*)alloc((size_t)S * KV_LORA * 4);
    ushort_t* o2h  = (ushort_t*)alloc((size_t)S * 2048 * 2);
    ushort_t* o2l  = (ushort_t*)alloc((size_t)S * 2048 * 2);
    ushort_t* qah  = (ushort_t*)alloc((size_t)S * 16 * 576 * 2);
    ushort_t* qal  = (ushort_t*)alloc((size_t)S * 16 * 576 * 2);
    ushort_t* kvh  = (ushort_t*)alloc((size_t)S * 576 * 2);
    ushort_t* kvl  = (ushort_t*)alloc((size_t)S * 576 * 2);
    // ---- Chunk-phase aliases over region A ----
    float* scb    = (float*)ws;
    ushort_t* pbh = (ushort_t*)(ws + (size_t)SCHUNK * 16 * 1024 * 4);
    ushort_t* pbl = pbh + (size_t)SCHUNK * 16 * 1024;
    ushort_t* o1h = (ushort_t*)(ws + (size_t)SCHUNK * 16 * 1024 * 8);
    ushort_t* o1l = o1h + (size_t)SCHUNK * 16 * 512;
    // ---- Final-GEMM aliases over scb region (dead after chunk loop) ----
    ushort_t* oph = (ushort_t*)ws;                        // 8.4 MB (o_proj split)
    ushort_t* opl = oph + (size_t)DIM * 2048;             // 8.4 MB

    // ---- split x and the packed x-proj weight [q_a | kv_a | idx_wk | idx_wp] to bf16 hi/lo ----
    split_kernel<<<S * DIM / 1024, 256, 0, stream>>>(x, xh, xl, S * DIM / 4);
    split_kernel<<<Q_LORA * DIM / 1024, 256, 0, stream>>>(q_a_proj, wpackh, wpackl, Q_LORA * DIM / 4);
    split_kernel<<<576 * DIM / 1024, 256, 0, stream>>>(kv_a_proj, wpackh + (size_t)1536 * DIM,
                                                       wpackl + (size_t)1536 * DIM, 576 * DIM / 4);
    split_kernel<<<128 * DIM / 1024, 256, 0, stream>>>(idx_wk, wpackh + (size_t)2112 * DIM,
                                                       wpackl + (size_t)2112 * DIM, 128 * DIM / 4);
    split_kernel<<<16 * DIM / 1024, 256, 0, stream>>>(idx_wp, wpackh + (size_t)2240 * DIM,
                                                      wpackl + (size_t)2240 * DIM, 16 * DIM / 4);
    hipMemsetAsync(wpackh + (size_t)XPLD * DIM, 0, (size_t)(XPLD_PAD - XPLD) * DIM * 2, stream);
    hipMemsetAsync(wpackl + (size_t)XPLD * DIM, 0, (size_t)(XPLD_PAD - XPLD) * DIM * 2, stream);
    // ---- fused x-projection: one GEMM N=2256 (grid padded to 2304) ----
    gemm3_lds<<<dim3((XPLD + 127) / 128, S / 128), 256, 0, stream>>>(xh, xl, wpackh, wpackl, xp, S, XPLD, DIM);
    rms_split_kernel<<<S, 256, 0, stream>>>(xp, qrh, qrl, q_a_ln_w, Q_LORA, XPLD);
    rms_kernel<<<S, 256, 0, stream>>>(xp + 1536, kv, kv_a_ln_w, KV_LORA, XPLD, KV_LORA);
    // ---- fused qr-projection: wq2 = [q_b | idx_wq_b] split (overwrites xh/xl region, dead) ----
    split_kernel<<<3072 * Q_LORA / 1024, 256, 0, stream>>>(q_b_proj, wq2h, wq2l, 3072 * Q_LORA / 4);
    split_kernel<<<2048 * Q_LORA / 1024, 256, 0, stream>>>(idx_wq_b, wq2h + (size_t)3072 * Q_LORA,
                                                           wq2l + (size_t)3072 * Q_LORA, 2048 * Q_LORA / 4);
    gemm3_lds<<<dim3(QLD / 128, S / 128), 256, 0, stream>>>(qrh, qrl, wq2h, wq2l, qib, S, QLD, Q_LORA);
    // ---- rope ----
    rope_inter_kernel<<<S * NH * 32 / 256, 256, 0, stream>>>(qib, fcos, fsin, NH, QK_HD, QK_NOPE, QLD);
    rope_inter_kernel<<<S * 32 / 256, 256, 0, stream>>>(xp + 1536, fcos, fsin, 1, 0, KV_LORA, XPLD);
    rope_half_kernel<<<S * NH * 32 / 256, 256, 0, stream>>>(qib + 3072, fcos, fsin, NH, 128, QLD);
    // ---- indexer ----
    ln_kernel<<<S, 128, 0, stream>>>(xp + 2112, iknw, iknb, XPLD);
    rope_half_kernel<<<S * 32 / 256, 256, 0, stream>>>(xp + 2112, fcos, fsin, 1, 0, XPLD);
    rotate_kernel<<<S * NH, 128, 0, stream>>>(qib + 3072, QLD, NH, iqr);
    rotate_kernel<<<S, 128, 0, stream>>>(xp + 2112, XPLD, 1, ikr);
    wq_kernel<<<S * NH * 128 / 256, 256, 0, stream>>>(xp + 2240, iqr);
    iscore_mfma<<<dim3(16, 16), 256, 0, stream>>>(iqr, ikr, isc);
    topk_kernel<<<S, 256, 0, stream>>>(isc, tk);
    // ---- attention prep (kvsplit/splitw2 after iscore: their buffers overlay iqr/ikr) ----
    w1t_kernel<<<dim3(8, 2, 16), 256, 0, stream>>>(kv_b, w1t);
    qabs_mfma<<<dim3(4, S / 128, 16), 256, 0, stream>>>(qib, w1t, qah, qal);
    qpe_split<<<S * NH * 64 / 256, 256, 0, stream>>>(qib, qah, qal);
    kvsplit_kernel<<<S, 576, 0, stream>>>(kv, xp + 1536, kvh, kvl, kvi);
    splitw2_kernel<<<1024, 256, 0, stream>>>(kv_b, w2h, w2l);
    // ---- attention chunks ----
    for (int c = 0; c < 4; ++c) {
        int s0 = c * SCHUNK;
        attn_score_mfma<<<SCHUNK * 4, 512, 0, stream>>>(qah, qal, kvh, kvl, tk, scb, s0);
        softmax_pb<<<SCHUNK * 16, 256, 0, stream>>>(scb, pbh, pbl);
        attn_pv_mfma<<<SCHUNK, 512, 0, stream>>>(pbh, pbl, kvi, tk, o1h, o1l, s0);
        outproj_mfma<<<dim3(4, 16), 256, 0, stream>>>(o1h, o1l, w2h, w2l, o2h, o2l, s0);
    }
    // ---- final projection: split o_proj into dead scb region, then pure-bf16x3 GEMM ----
    split_kernel<<<DIM * 2048 / 1024, 256, 0, stream>>>(o_proj, oph, opl, DIM * 2048 / 4);
    gemm3_lds<<<dim3(DIM / 128, S / 128), 256, 0, stream>>>(o2h, o2l, oph, opl, out, S, DIM, NH * V_HD);
}

// Round 6
// 1515.138 us; speedup vs baseline: 1.1027x; 1.1027x over previous
//
#include <hip/hip_runtime.h>
#include <hip/hip_bf16.h>
#include <math.h>

#define S 2048
#define NH 16
#define DIM 2048
#define QK_NOPE 128
#define QK_ROPE 64
#define QK_HD 192
#define V_HD 128
#define Q_LORA 1536
#define KV_LORA 512
#define IDX_HD 128
#define SM_SCALE 0.07216878364870323f
#define SCHUNK 512
#define PADK 40
#define XPLD 2256   // packed x-proj output row stride: [qr 1536 | kvp 576 | ikf 128 | iw 16]
#define QLD 5120    // packed qr-proj output row stride: [q 3072 | iqf 2048]
#define XPLD_PAD 2304  // B rows padded to 128 multiple for the x-proj GEMM

typedef __hip_bfloat16 bf16;
typedef unsigned short ushort_t;
typedef __attribute__((ext_vector_type(8))) short short8;
typedef __attribute__((ext_vector_type(4))) float f32x4;

__device__ __forceinline__ f32x4 mfma_bf16(short8 a, short8 b, f32x4 c) {
    return __builtin_amdgcn_mfma_f32_16x16x32_bf16(a, b, c, 0, 0, 0);
}
__device__ __forceinline__ void async16(const void* g, void* l) {
    __builtin_amdgcn_global_load_lds((const __attribute__((address_space(1))) void*)g,
                                     (__attribute__((address_space(3))) void*)l, 16, 0, 0);
}
__device__ __forceinline__ unsigned short f2bf(float f) {  // RNE
    unsigned int u = __float_as_uint(f);
    return (unsigned short)((u + 0x7fff + ((u >> 16) & 1)) >> 16);
}
__device__ __forceinline__ float bf2f(unsigned short b) {
    return __uint_as_float(((unsigned int)b) << 16);
}

// ---------------- fp32 -> bf16 hi/lo split (packed, n4 = elems/4) ----------------
__global__ __launch_bounds__(256) void split_kernel(const float* __restrict__ in, ushort_t* __restrict__ hi,
                                                    ushort_t* __restrict__ lo, int n4) {
    int idx = blockIdx.x * 256 + threadIdx.x;
    if (idx >= n4) return;
    float4 v = ((const float4*)in)[idx];
    ushort4 h, l;
    h.x = f2bf(v.x); l.x = f2bf(v.x - bf2f(h.x));
    h.y = f2bf(v.y); l.y = f2bf(v.y - bf2f(h.y));
    h.z = f2bf(v.z); l.z = f2bf(v.z - bf2f(h.z));
    h.w = f2bf(v.w); l.w = f2bf(v.w - bf2f(h.w));
    ((ushort4*)hi)[idx] = h;
    ((ushort4*)lo)[idx] = l;
}

// ---------------- strided split of kv_b V-half: w2[h][128][512] <- kv_b[h*256+128+r][512] ----------------
__global__ __launch_bounds__(256) void splitw2_kernel(const float* __restrict__ kv_b,
                                                      ushort_t* __restrict__ w2h, ushort_t* __restrict__ w2l) {
    int idx = blockIdx.x * 256 + threadIdx.x;       // 262144 quads
    int h = idx >> 14, rem = idx & 16383;
    int row = rem >> 7, c4 = (rem & 127) * 4;
    float4 v = *(const float4*)(kv_b + ((size_t)(h * 256 + 128 + row)) * 512 + c4);
    ushort4 hh, ll;
    hh.x = f2bf(v.x); ll.x = f2bf(v.x - bf2f(hh.x));
    hh.y = f2bf(v.y); ll.y = f2bf(v.y - bf2f(hh.y));
    hh.z = f2bf(v.z); ll.z = f2bf(v.z - bf2f(hh.z));
    hh.w = f2bf(v.w); ll.w = f2bf(v.w - bf2f(hh.w));
    *(ushort4*)(w2h + ((size_t)(h * 128 + row)) * 512 + c4) = hh;
    *(ushort4*)(w2l + ((size_t)(h * 128 + row)) * 512 + c4) = ll;
}

// ---------------- pre-split bf16x3 MFMA GEMM: C[M,N] = (Ah+Al)[M,K] @ (Bh+Bl)[N,K]^T ----------------
__global__ __launch_bounds__(256) void gemm3_lds(const ushort_t* __restrict__ Ah, const ushort_t* __restrict__ Al,
                                                 const ushort_t* __restrict__ Bh, const ushort_t* __restrict__ Bl,
                                                 float* __restrict__ C, int M, int N, int K) {
    __shared__ ushort_t sAh[128 * 32], sAl[128 * 32], sBh[128 * 32], sBl[128 * 32];
    const int tid = threadIdx.x;
    const int bm = blockIdx.y * 128, bn = blockIdx.x * 128;
    const int w = tid >> 6, lane = tid & 63;
    const int wm = (w >> 1) * 64, wn = (w & 1) * 64;
    const int fr = lane & 15, fk = (lane >> 4) * 8;
    const int srow = tid >> 2, skc = (tid & 3) * 8;
    f32x4 acc[4][4];
    for (int i = 0; i < 4; ++i)
        for (int j = 0; j < 4; ++j) acc[i][j] = f32x4{0.f, 0.f, 0.f, 0.f};
    const ushort_t* pAh0 = Ah + (size_t)(bm + srow) * K + skc;
    const ushort_t* pAh1 = Ah + (size_t)(bm + 64 + srow) * K + skc;
    const ushort_t* pAl0 = Al + (size_t)(bm + srow) * K + skc;
    const ushort_t* pAl1 = Al + (size_t)(bm + 64 + srow) * K + skc;
    const ushort_t* pBh0 = Bh + (size_t)(bn + srow) * K + skc;
    const ushort_t* pBh1 = Bh + (size_t)(bn + 64 + srow) * K + skc;
    const ushort_t* pBl0 = Bl + (size_t)(bn + srow) * K + skc;
    const ushort_t* pBl1 = Bl + (size_t)(bn + 64 + srow) * K + skc;
    ushort_t* dA0 = &sAh[srow * 32 + skc];
    ushort_t* dA1 = &sAh[(64 + srow) * 32 + skc];
    ushort_t* dAl0 = &sAl[srow * 32 + skc];
    ushort_t* dAl1 = &sAl[(64 + srow) * 32 + skc];
    ushort_t* dB0 = &sBh[srow * 32 + skc];
    ushort_t* dB1 = &sBh[(64 + srow) * 32 + skc];
    ushort_t* dBl0 = &sBl[srow * 32 + skc];
    ushort_t* dBl1 = &sBl[(64 + srow) * 32 + skc];
    for (int k0 = 0; k0 < K; k0 += 32) {
        __syncthreads();
        async16(pAh0, dA0);  async16(pAh1, dA1);
        async16(pAl0, dAl0); async16(pAl1, dAl1);
        async16(pBh0, dB0);  async16(pBh1, dB1);
        async16(pBl0, dBl0); async16(pBl1, dBl1);
        pAh0 += 32; pAh1 += 32; pAl0 += 32; pAl1 += 32;
        pBh0 += 32; pBh1 += 32; pBl0 += 32; pBl1 += 32;
        __syncthreads();
        short8 ahf[4], alf[4], bhf[4], blf[4];
        for (int i = 0; i < 4; ++i) {
            int ro = (wm + i * 16 + fr) * 32 + fk;
            ahf[i] = *(const short8*)&sAh[ro];
            alf[i] = *(const short8*)&sAl[ro];
        }
        for (int j = 0; j < 4; ++j) {
            int ro = (wn + j * 16 + fr) * 32 + fk;
            bhf[j] = *(const short8*)&sBh[ro];
            blf[j] = *(const short8*)&sBl[ro];
        }
        for (int i = 0; i < 4; ++i)
            for (int j = 0; j < 4; ++j) {
                acc[i][j] = mfma_bf16(ahf[i], bhf[j], acc[i][j]);
                acc[i][j] = mfma_bf16(ahf[i], blf[j], acc[i][j]);
                acc[i][j] = mfma_bf16(alf[i], bhf[j], acc[i][j]);
            }
    }
    const int cr = (lane >> 4) * 4, cc = lane & 15;
    for (int i = 0; i < 4; ++i)
        for (int j = 0; j < 4; ++j) {
            int row = bm + wm + i * 16 + cr;
            int col = bn + wn + j * 16 + cc;
            if (col < N)
                for (int r = 0; r < 4; ++r)
                    C[(size_t)(row + r) * N + col] = acc[i][j][r];
        }
}

// ---------------- RMSNorm (strided in, fp32 out) ----------------
__global__ __launch_bounds__(256) void rms_kernel(const float* __restrict__ in, float* __restrict__ out,
                                                  const float* __restrict__ w, int C, int ldin, int ldout) {
    const int row = blockIdx.x;
    const float* xr = in + (size_t)row * ldin;
    float* yr = out + (size_t)row * ldout;
    float ss = 0.f;
    for (int c = threadIdx.x; c < C; c += 256) { float v = xr[c]; ss += v * v; }
    for (int o = 32; o; o >>= 1) ss += __shfl_down(ss, o, 64);
    __shared__ float red[4];
    const int wave = threadIdx.x >> 6, lane = threadIdx.x & 63;
    if (lane == 0) red[wave] = ss;
    __syncthreads();
    const float tot = red[0] + red[1] + red[2] + red[3];
    const float scale = rsqrtf(tot / (float)C + 1e-6f);
    for (int c = threadIdx.x; c < C; c += 256) yr[c] = w[c] * (xr[c] * scale);
}

// ---------------- RMSNorm (strided in, bf16 hi/lo packed out) ----------------
__global__ __launch_bounds__(256) void rms_split_kernel(const float* __restrict__ in, ushort_t* __restrict__ hi,
                                                        ushort_t* __restrict__ lo, const float* __restrict__ w,
                                                        int C, int ldin) {
    const int row = blockIdx.x;
    const float* xr = in + (size_t)row * ldin;
    float ss = 0.f;
    for (int c = threadIdx.x; c < C; c += 256) { float v = xr[c]; ss += v * v; }
    for (int o = 32; o; o >>= 1) ss += __shfl_down(ss, o, 64);
    __shared__ float red[4];
    const int wave = threadIdx.x >> 6, lane = threadIdx.x & 63;
    if (lane == 0) red[wave] = ss;
    __syncthreads();
    const float tot = red[0] + red[1] + red[2] + red[3];
    const float scale = rsqrtf(tot / (float)C + 1e-6f);
    for (int c = threadIdx.x; c < C; c += 256) {
        float v = w[c] * (xr[c] * scale);
        unsigned short h = f2bf(v);
        hi[(size_t)row * C + c] = h;
        lo[(size_t)row * C + c] = f2bf(v - bf2f(h));
    }
}

// ---------------- LayerNorm row length 128 (strided, in place) ----------------
__global__ __launch_bounds__(128) void ln_kernel(float* __restrict__ x, const float* __restrict__ w,
                                                 const float* __restrict__ b, int ld) {
    const int row = blockIdx.x;
    float* xr = x + (size_t)row * ld;
    const int tid = threadIdx.x;
    float v = xr[tid];
    float sm = v;
    for (int o = 32; o; o >>= 1) sm += __shfl_down(sm, o, 64);
    __shared__ float red[2];
    if ((tid & 63) == 0) red[tid >> 6] = sm;
    __syncthreads();
    const float mu = (red[0] + red[1]) * (1.f / 128.f);
    __syncthreads();
    float d = v - mu;
    float sv = d * d;
    for (int o = 32; o; o >>= 1) sv += __shfl_down(sv, o, 64);
    if ((tid & 63) == 0) red[tid >> 6] = sv;
    __syncthreads();
    const float var = (red[0] + red[1]) * (1.f / 128.f);
    const float rs = rsqrtf(var + 1e-6f);
    xr[tid] = (v - mu) * rs * w[tid] + b[tid];
}

// ---------------- RoPE interleaved: p = X + s*ld + h*hs + off ----------------
__global__ __launch_bounds__(256) void rope_inter_kernel(float* __restrict__ X, const float* __restrict__ ct,
                                                         const float* __restrict__ st, int H, int hs, int off,
                                                         int ld) {
    int idx = blockIdx.x * 256 + threadIdx.x;
    int k = idx & 31;
    int h = (idx >> 5) % H;
    int s = idx / (32 * H);
    if (s >= S) return;
    float c = ct[s * 32 + k], sn = st[s * 32 + k];
    float* p = X + (size_t)s * ld + h * hs + off;
    float x1 = p[2 * k], x2 = p[2 * k + 1];
    p[2 * k]     = x1 * c - x2 * sn;
    p[2 * k + 1] = x1 * sn + x2 * c;
}

// ---------------- RoPE half: p = X + s*ld + h*hs; soff = first query row ----------------
__global__ __launch_bounds__(256) void rope_half_kernel(float* __restrict__ X, const float* __restrict__ ct,
                                                        const float* __restrict__ st, int H, int hs, int ld,
                                                        int soff) {
    int idx = blockIdx.x * 256 + threadIdx.x;
    int k = idx & 31;
    int h = (idx >> 5) % H;
    int s = idx / (32 * H) + soff;
    if (s >= S) return;
    float c = ct[s * 32 + k], sn = st[s * 32 + k];
    float* p = X + (size_t)s * ld + h * hs;
    float x1 = p[k], x2 = p[32 + k];
    p[k]      = x1 * c - x2 * sn;
    p[32 + k] = x1 * sn + x2 * c;
}

// ---------------- Hadamard rotate: in strided (s*lds + h*128), out packed r*128; roff = first (s,h) ----------------
__global__ __launch_bounds__(128) void rotate_kernel(const float* __restrict__ in, int lds, int H,
                                                     bf16* __restrict__ out, int roff) {
    __shared__ float xs[128];
    const int r = blockIdx.x + roff, j = threadIdx.x;
    const int s = r / H, h = r - s * H;
    float v = in[(size_t)s * lds + h * 128 + j];
    xs[j] = __bfloat162float(__float2bfloat16(v));
    __syncthreads();
    float acc = 0.f;
    for (int d = 0; d < 128; ++d) {
        float xv = xs[d];
        acc += (__popc(d & j) & 1) ? -xv : xv;
    }
    float t = __bfloat162float(__float2bfloat16(acc)) * 0.08838834764831845f;
    out[(size_t)r * 128 + j] = __float2bfloat16(t);
}

// ---------------- wq scale: iw read from strided xp slice; 0.25 folded here; ioff = first element ----------------
__global__ __launch_bounds__(256) void wq_kernel(const float* __restrict__ iwb, bf16* __restrict__ iqr,
                                                 int ioff) {
    int idx = blockIdx.x * 256 + threadIdx.x + ioff;
    int s = idx >> 11, h = (idx >> 7) & 15;
    float a = 0.25f * iwb[(size_t)s * XPLD + h];
    float v = __bfloat162float(iqr[idx]);
    float t = (a * v) * 0.08838834764831845f;
    iqr[idx] = __float2bfloat16(t);
}

// ---------------- index score via bf16 MFMA — only query rows s >= 1024 (s < 1024 never read) ----------------
__global__ __launch_bounds__(256) void iscore_mfma(const bf16* __restrict__ wq, const bf16* __restrict__ ik,
                                                   float* __restrict__ out) {
    if (blockIdx.x > blockIdx.y + 8) return;
    __shared__ unsigned short As[128 * 32], Bs[128 * 32];
    const int bs = (blockIdx.y + 8) * 128, bt = blockIdx.x * 128;
    const int tid = threadIdx.x, w = tid >> 6, lane = tid & 63;
    const int wm = (w >> 1) * 64, wn = (w & 1) * 64;
    const int fr = lane & 15, fk = (lane >> 4) * 8;
    const int srow = lane >> 2, skc = (lane & 3) * 8;
    f32x4 sum[4][4];
    for (int i = 0; i < 4; ++i)
        for (int j = 0; j < 4; ++j) sum[i][j] = f32x4{0.f, 0.f, 0.f, 0.f};
    for (int h = 0; h < 16; ++h) {
        f32x4 acc[4][4];
        for (int i = 0; i < 4; ++i)
            for (int j = 0; j < 4; ++j) acc[i][j] = f32x4{0.f, 0.f, 0.f, 0.f};
        for (int k0 = 0; k0 < 128; k0 += 32) {
            __syncthreads();
            for (int i = 0; i < 2; ++i) {
                int seg = i * 4 + w;
                async16(wq + (size_t)(bs + seg * 16 + srow) * 2048 + h * 128 + k0 + skc, &As[seg * 512]);
                async16(ik + (size_t)(bt + seg * 16 + srow) * 128 + k0 + skc, &Bs[seg * 512]);
            }
            __syncthreads();
            short8 af[4], bff[4];
            for (int i = 0; i < 4; ++i) af[i]  = *(const short8*)&As[(wm + i * 16 + fr) * 32 + fk];
            for (int j = 0; j < 4; ++j) bff[j] = *(const short8*)&Bs[(wn + j * 16 + fr) * 32 + fk];
            for (int i = 0; i < 4; ++i)
                for (int j = 0; j < 4; ++j)
                    acc[i][j] = mfma_bf16(af[i], bff[j], acc[i][j]);
        }
        for (int i = 0; i < 4; ++i)
            for (int j = 0; j < 4; ++j)
                for (int r = 0; r < 4; ++r)
                    sum[i][j][r] += fmaxf(acc[i][j][r], 0.f);
    }
    const int cr = (lane >> 4) * 4, cc = lane & 15;
    for (int i = 0; i < 4; ++i)
        for (int j = 0; j < 4; ++j)
            for (int r = 0; r < 4; ++r)
                out[(size_t)(bs + wm + i * 16 + cr + r) * 2048 + bt + wn + j * 16 + cc] = sum[i][j][r];
}

// ---------------- top-k (launched only for s >= s0 = 1024; s < 1024 is dense-causal, tk unused) ----------------
__global__ __launch_bounds__(256) void topk_kernel(const float* __restrict__ isc, int* __restrict__ tk,
                                                   int s0) {
    __shared__ unsigned long long keys[2048];
    const int s = s0 + blockIdx.x;
    const float* row = isc + (size_t)s * 2048;
    for (int t = threadIdx.x; t < 2048; t += 256) {
        unsigned long long kk = 0ull;
        if (t <= s) {
            unsigned int vb = __float_as_uint(row[t]);
            kk = ((unsigned long long)vb << 32) | (unsigned int)(2048 - t);
        }
        keys[t] = kk;
    }
    __syncthreads();
    for (int k = 2; k <= 2048; k <<= 1) {
        for (int j = k >> 1; j > 0; j >>= 1) {
            for (int t = threadIdx.x; t < 2048; t += 256) {
                int l = t ^ j;
                if (l > t) {
                    bool up = ((t & k) == 0);
                    unsigned long long a = keys[t], b = keys[l];
                    bool sw = up ? (a < b) : (a > b);
                    if (sw) { keys[t] = b; keys[l] = a; }
                }
            }
            __syncthreads();
        }
    }
    const int cnt = min(1024, s + 1);
    for (int i = threadIdx.x; i < 1024; i += 256) {
        int t = (i < cnt) ? (2048 - (int)(keys[i] & 0xFFFFFFFFull)) : -1;
        tk[(size_t)s * 1024 + i] = t;
    }
}

// ---------------- transpose kv_b head-1 part ----------------
__global__ __launch_bounds__(256) void w1t_kernel(const float* __restrict__ kv_b, float* __restrict__ w1t) {
    __shared__ float ts[64][65];
    const int cb = blockIdx.x * 64, db = blockIdx.y * 64, h = blockIdx.z;
    const int t = threadIdx.x;
    for (int it = 0; it < 16; ++it) {
        int idx = it * 256 + t;
        int rr = idx >> 6, cc = idx & 63;
        ts[rr][cc] = kv_b[(size_t)(h * 256 + db + rr) * 512 + cb + cc];
    }
    __syncthreads();
    for (int it = 0; it < 16; ++it) {
        int idx = it * 256 + t;
        int rr = idx >> 6, cc = idx & 63;
        w1t[(size_t)h * 65536 + (size_t)(cb + rr) * 128 + db + cc] = ts[cc][rr];
    }
}

// ---------------- kv split: hi/lo rows of 576 for score; packed u32 {hi,lo} V rows for pv ----------------
__global__ __launch_bounds__(576) void kvsplit_kernel(const float* __restrict__ kv, const float* __restrict__ kpe,
                                                      ushort_t* __restrict__ kvh, ushort_t* __restrict__ kvl,
                                                      unsigned int* __restrict__ kvi) {
    const int t = blockIdx.x, c = threadIdx.x;
    float v = (c < 512) ? kv[(size_t)t * 512 + c] : kpe[(size_t)t * XPLD + c];
    unsigned short hi = f2bf(v);
    unsigned short lo = f2bf(v - bf2f(hi));
    kvh[(size_t)t * 576 + c] = hi;
    kvl[(size_t)t * 576 + c] = lo;
    if (c < 512) kvi[(size_t)t * 512 + c] = (unsigned int)hi | ((unsigned int)lo << 16);
}

// ---------------- qabs via bf16x3 MFMA (q strided from packed qib) ----------------
__global__ __launch_bounds__(256) void qabs_mfma(const float* __restrict__ q, const float* __restrict__ w1t,
                                                 ushort_t* __restrict__ qah, ushort_t* __restrict__ qal) {
    __shared__ unsigned short Ah[128 * PADK], Al[128 * PADK], Bh[128 * PADK], Bl[128 * PADK];
    const int tid = threadIdx.x;
    const int bn = blockIdx.x * 128, bm = blockIdx.y * 128, h = blockIdx.z;
    const int w = tid >> 6, lane = tid & 63;
    const int wm = (w >> 1) * 64, wn = (w & 1) * 64;
    const int fr = lane & 15, fk = (lane >> 4) * 8;
    f32x4 acc[4][4];
    for (int i = 0; i < 4; ++i)
        for (int j = 0; j < 4; ++j) acc[i][j] = f32x4{0.f, 0.f, 0.f, 0.f};
    for (int k0 = 0; k0 < 128; k0 += 32) {
        __syncthreads();
        for (int it = 0; it < 4; ++it) {
            int f = it * 256 + tid;
            int row = f >> 3, kc = (f & 7) * 4;
            float4 av = *(const float4*)(q + (size_t)(bm + row) * QLD + h * QK_HD + k0 + kc);
            float4 bv = *(const float4*)(w1t + (size_t)h * 65536 + (size_t)(bn + row) * 128 + k0 + kc);
            ushort4 ahi, alo, bhi, blo;
            ahi.x = f2bf(av.x); alo.x = f2bf(av.x - bf2f(ahi.x));
            ahi.y = f2bf(av.y); alo.y = f2bf(av.y - bf2f(ahi.y));
            ahi.z = f2bf(av.z); alo.z = f2bf(av.z - bf2f(ahi.z));
            ahi.w = f2bf(av.w); alo.w = f2bf(av.w - bf2f(ahi.w));
            bhi.x = f2bf(bv.x); blo.x = f2bf(bv.x - bf2f(bhi.x));
            bhi.y = f2bf(bv.y); blo.y = f2bf(bv.y - bf2f(bhi.y));
            bhi.z = f2bf(bv.z); blo.z = f2bf(bv.z - bf2f(bhi.z));
            bhi.w = f2bf(bv.w); blo.w = f2bf(bv.w - bf2f(bhi.w));
            *(ushort4*)&Ah[row * PADK + kc] = ahi;
            *(ushort4*)&Al[row * PADK + kc] = alo;
            *(ushort4*)&Bh[row * PADK + kc] = bhi;
            *(ushort4*)&Bl[row * PADK + kc] = blo;
        }
        __syncthreads();
        short8 ahf[4], alf[4], bhf[4], blf[4];
        for (int i = 0; i < 4; ++i) {
            int ro = (wm + i * 16 + fr) * PADK + fk;
            ahf[i] = *(const short8*)&Ah[ro];
            alf[i] = *(const short8*)&Al[ro];
        }
        for (int j = 0; j < 4; ++j) {
            int ro = (wn + j * 16 + fr) * PADK + fk;
            bhf[j] = *(const short8*)&Bh[ro];
            blf[j] = *(const short8*)&Bl[ro];
        }
        for (int i = 0; i < 4; ++i)
            for (int j = 0; j < 4; ++j) {
                acc[i][j] = mfma_bf16(ahf[i], bhf[j], acc[i][j]);
                acc[i][j] = mfma_bf16(ahf[i], blf[j], acc[i][j]);
                acc[i][j] = mfma_bf16(alf[i], bhf[j], acc[i][j]);
            }
    }
    const int cr = (lane >> 4) * 4, cc = lane & 15;
    for (int i = 0; i < 4; ++i)
        for (int j = 0; j < 4; ++j)
            for (int r = 0; r < 4; ++r) {
                int srow = bm + wm + i * 16 + cr + r;
                int col = bn + wn + j * 16 + cc;
                float f = acc[i][j][r] * SM_SCALE;
                size_t addr = ((size_t)srow * 16 + h) * 576 + col;
                unsigned short hi = f2bf(f);
                qah[addr] = hi;
                qal[addr] = f2bf(f - bf2f(hi));
            }
}

// ---------------- qpe split (q strided from packed qib) ----------------
__global__ __launch_bounds__(256) void qpe_split(const float* __restrict__ q, ushort_t* __restrict__ qah,
                                                 ushort_t* __restrict__ qal) {
    int idx = blockIdx.x * 256 + threadIdx.x;
    int r = idx & 63, h = (idx >> 6) & 15, s = idx >> 10;
    float f = q[(size_t)s * QLD + h * QK_HD + 128 + r] * SM_SCALE;
    size_t addr = ((size_t)s * 16 + h) * 576 + 512 + r;
    unsigned short hi = f2bf(f);
    qah[addr] = hi;
    qal[addr] = f2bf(f - bf2f(hi));
}

// ---------------- attn_score via MFMA bf16x3 — 2-phase pipelined, pass-split grid ----------------
// dense=1 (queries s<1024): top-k of min(1024,s+1) causal keys selects ALL of {0..s} (just permuted);
// softmax+PV are permutation-invariant, so use identity ordering -> sequential K rows, no tk read,
// all blocks stream the same rows (L2-shared) instead of per-query scattered gathers.
__global__ __launch_bounds__(512) void attn_score_mfma(const ushort_t* __restrict__ qah,
                                                       const ushort_t* __restrict__ qal,
                                                       const ushort_t* __restrict__ kvh,
                                                       const ushort_t* __restrict__ kvl,
                                                       const int* __restrict__ tk,
                                                       float* __restrict__ scb, int s0, int dense) {
    const int sl = blockIdx.x, s = s0 + sl, pass = blockIdx.y;
    const int tid = threadIdx.x, w = tid >> 6, lane = tid & 63;
    const int cnt = min(1024, s + 1);
    if (pass * 256 >= cnt) {  // whole pass masked: write NEG and exit (no gather)
        for (int i = tid; i < 4096; i += 512) {
            int head = i >> 8, key = i & 255;
            scb[((size_t)sl * 16 + head) * 1024 + pass * 256 + key] = -1e30f;
        }
        return;
    }
    __shared__ int tks[256];
    __shared__ __align__(16) ushort_t kh[2][8192], kl[2][8192];
    if (tid < 256) {
        if (dense) {
            tks[tid] = pass * 256 + tid;
        } else {
            int t = tk[(size_t)s * 1024 + pass * 256 + tid];
            tks[tid] = t < 0 ? 0 : t;
        }
    }
    __syncthreads();
    const int fr = lane & 15, g = lane >> 4;
    const size_t abase = ((size_t)s * 16 + fr) * 576 + g * 8;
    const int R0 = tid >> 2;
    const int sw = (tid & 3) ^ ((R0 >> 1) & 3);
    const size_t t0 = (size_t)tks[R0], t1 = (size_t)tks[R0 + 128];
    const ushort_t* gh0 = kvh + t0 * 576 + sw * 8;
    const ushort_t* gh1 = kvh + t1 * 576 + sw * 8;
    const ushort_t* gl0 = kvl + t0 * 576 + sw * 8;
    const ushort_t* gl1 = kvl + t1 * 576 + sw * 8;
    const int ro_a = (w * 32 + fr) * 32 + ((g ^ ((fr >> 1) & 3)) << 3);
    async16(gh0, &kh[0][w * 512]);
    async16(gh1, &kh[0][4096 + w * 512]);
    async16(gl0, &kl[0][w * 512]);
    async16(gl1, &kl[0][4096 + w * 512]);
    short8 qh = *(const short8*)(qah + abase);
    short8 ql = *(const short8*)(qal + abase);
    f32x4 acc0 = {0.f, 0.f, 0.f, 0.f}, acc1 = {0.f, 0.f, 0.f, 0.f};
    int cur = 0;
    __syncthreads();
    for (int ch = 0; ch < 18; ++ch) {
        if (ch < 17) {
            int off = (ch + 1) * 32;
            async16(gh0 + off, &kh[cur ^ 1][w * 512]);
            async16(gh1 + off, &kh[cur ^ 1][4096 + w * 512]);
            async16(gl0 + off, &kl[cur ^ 1][w * 512]);
            async16(gl1 + off, &kl[cur ^ 1][4096 + w * 512]);
        }
        short8 qhc = qh, qlc = ql;
        if (ch < 17) {
            qh = *(const short8*)(qah + abase + (ch + 1) * 32);
            ql = *(const short8*)(qal + abase + (ch + 1) * 32);
        }
        short8 bh0 = *(const short8*)&kh[cur][ro_a];
        short8 bl0 = *(const short8*)&kl[cur][ro_a];
        short8 bh1 = *(const short8*)&kh[cur][ro_a + 512];
        short8 bl1 = *(const short8*)&kl[cur][ro_a + 512];
        acc0 = mfma_bf16(qhc, bh0, acc0);
        acc0 = mfma_bf16(qhc, bl0, acc0);
        acc0 = mfma_bf16(qlc, bh0, acc0);
        acc1 = mfma_bf16(qhc, bh1, acc1);
        acc1 = mfma_bf16(qhc, bl1, acc1);
        acc1 = mfma_bf16(qlc, bh1, acc1);
        __syncthreads();
        cur ^= 1;
    }
    const int cr = (lane >> 4) * 4, cc = lane & 15;
    for (int r = 0; r < 4; ++r) {
        int head = cr + r;
        int key0 = pass * 256 + w * 32 + cc;
        int key1 = key0 + 16;
        scb[((size_t)sl * 16 + head) * 1024 + key0] = (key0 < cnt) ? acc0[r] : -1e30f;
        scb[((size_t)sl * 16 + head) * 1024 + key1] = (key1 < cnt) ? acc1[r] : -1e30f;
    }
}

// ---------------- softmax -> p as bf16 hi/lo ----------------
__global__ __launch_bounds__(256) void softmax_pb(const float* __restrict__ scb,
                                                  ushort_t* __restrict__ pbh, ushort_t* __restrict__ pbl) {
    const size_t row = blockIdx.x;
    const float* src = scb + row * 1024;
    const int tid = threadIdx.x, wave = tid >> 6, lane = tid & 63;
    __shared__ float red[4];
    float v[4];
    float m = -INFINITY;
    for (int i = 0; i < 4; ++i) { v[i] = src[tid + 256 * i]; m = fmaxf(m, v[i]); }
    for (int o = 32; o; o >>= 1) m = fmaxf(m, __shfl_down(m, o, 64));
    if (lane == 0) red[wave] = m;
    __syncthreads();
    m = fmaxf(fmaxf(red[0], red[1]), fmaxf(red[2], red[3]));
    __syncthreads();
    float e[4], l = 0.f;
    for (int i = 0; i < 4; ++i) { e[i] = __expf(v[i] - m); l += e[i]; }
    for (int o = 32; o; o >>= 1) l += __shfl_down(l, o, 64);
    if (lane == 0) red[wave] = l;
    __syncthreads();
    const float il = 1.f / (red[0] + red[1] + red[2] + red[3]);
    for (int i = 0; i < 4; ++i) {
        float p = e[i] * il;
        unsigned short hi = f2bf(p);
        pbh[row * 1024 + tid + 256 * i] = hi;
        pbl[row * 1024 + tid + 256 * i] = f2bf(p - bf2f(hi));
    }
}

// ---------------- attn_pv via MFMA bf16x3 — packed {hi,lo} V, NAMED-reg prefetch (rule #20) ----
// dense=1: identity key ordering (see attn_score comment) -> sequential V rows shared across blocks.
#define PV_GATHER(KC)                                                                    \
    g0 = *(const uint4*)(kvi + (size_t)tks[(KC) * 32 + r0     ] * 512 + gp4);            \
    g1 = *(const uint4*)(kvi + (size_t)tks[(KC) * 32 + r0 + 4 ] * 512 + gp4);            \
    g2 = *(const uint4*)(kvi + (size_t)tks[(KC) * 32 + r0 + 8 ] * 512 + gp4);            \
    g3 = *(const uint4*)(kvi + (size_t)tks[(KC) * 32 + r0 + 12] * 512 + gp4);            \
    g4 = *(const uint4*)(kvi + (size_t)tks[(KC) * 32 + r0 + 16] * 512 + gp4);            \
    g5 = *(const uint4*)(kvi + (size_t)tks[(KC) * 32 + r0 + 20] * 512 + gp4);            \
    g6 = *(const uint4*)(kvi + (size_t)tks[(KC) * 32 + r0 + 24] * 512 + gp4);            \
    g7 = *(const uint4*)(kvi + (size_t)tks[(KC) * 32 + r0 + 28] * 512 + gp4);
#define PV_STORE()                                                                       \
    *(uint4*)&vt[(r0     ) * 512 + ((gp ^ 0) << 2)] = g0;                                \
    *(uint4*)&vt[(r0 + 4 ) * 512 + ((gp ^ 0) << 2)] = g1;                                \
    *(uint4*)&vt[(r0 + 8 ) * 512 + ((gp ^ 2) << 2)] = g2;                                \
    *(uint4*)&vt[(r0 + 12) * 512 + ((gp ^ 2) << 2)] = g3;                                \
    *(uint4*)&vt[(r0 + 16) * 512 + ((gp ^ 4) << 2)] = g4;                                \
    *(uint4*)&vt[(r0 + 20) * 512 + ((gp ^ 4) << 2)] = g5;                                \
    *(uint4*)&vt[(r0 + 24) * 512 + ((gp ^ 6) << 2)] = g6;                                \
    *(uint4*)&vt[(r0 + 28) * 512 + ((gp ^ 6) << 2)] = g7;
__global__ __launch_bounds__(512) void attn_pv_mfma(const ushort_t* __restrict__ pbh,
                                                    const ushort_t* __restrict__ pbl,
                                                    const unsigned int* __restrict__ kvi,
                                                    const int* __restrict__ tk,
                                                    ushort_t* __restrict__ o1h, ushort_t* __restrict__ o1l,
                                                    int s0, int dense) {
    const int sl = blockIdx.x, s = s0 + sl;
    const int tid = threadIdx.x, w = tid >> 6, lane = tid & 63;
    __shared__ int tks[1024];
    __shared__ unsigned int vt[32 * 512];   // 64 KiB
    for (int j = tid; j < 1024; j += 512) {
        if (dense) {
            tks[j] = j;
        } else {
            int t = tk[(size_t)s * 1024 + j];
            tks[j] = t < 0 ? 0 : t;
        }
    }
    const int fr = lane & 15, g = lane >> 4, fko = g * 8;
    const int r0 = tid >> 7;        // 0..3
    const int gp = tid & 127;       // 16B granule column (4 u32)
    const int gp4 = gp * 4;
    f32x4 acc[4];
    for (int i = 0; i < 4; ++i) acc[i] = f32x4{0.f, 0.f, 0.f, 0.f};
    const size_t pbase = ((size_t)sl * 16 + fr) * 1024 + fko;
    uint4 g0, g1, g2, g3, g4, g5, g6, g7;
    __syncthreads();                // tks ready
    PV_GATHER(0)
    PV_STORE()
    __syncthreads();                // vt chunk 0 ready
    for (int kc = 0; kc < 32; ++kc) {
        if (kc < 31) {              // prefetch next chunk into named regs (coalesced 1KB per wave)
            PV_GATHER(kc + 1)
        }
        short8 ph = *(const short8*)(pbh + pbase + kc * 32);
        short8 pl = *(const short8*)(pbl + pbase + kc * 32);
        #pragma unroll
        for (int sub = 0; sub < 4; ++sub) {
            const int cb = (w * 64 + sub * 16 + fr) ^ (g << 3);
            short8 bh, bl;
            #pragma unroll
            for (int jj = 0; jj < 8; ++jj) {
                const unsigned int v = vt[(fko + jj) * 512 + cb];
                bh[jj] = (short)(v & 0xffffu);
                bl[jj] = (short)(v >> 16);
            }
            acc[sub] = mfma_bf16(ph, bh, acc[sub]);
            acc[sub] = mfma_bf16(pl, bh, acc[sub]);
            acc[sub] = mfma_bf16(ph, bl, acc[sub]);
        }
        __syncthreads();            // all waves done reading vt
        if (kc < 31) {
            PV_STORE()
            __syncthreads();        // vt next chunk ready
        }
    }
    const int cr = (lane >> 4) * 4, cc = lane & 15;
    for (int sub = 0; sub < 4; ++sub)
        for (int r = 0; r < 4; ++r) {
            int head = cr + r, c = w * 64 + sub * 16 + cc;
            float f = acc[sub][r];
            unsigned short hv = f2bf(f);
            size_t addr = ((size_t)sl * 16 + head) * 512 + c;
            o1h[addr] = hv;
            o1l[addr] = f2bf(f - bf2f(hv));
        }
}

// ---------------- outproj via pre-split bf16x3 MFMA (gemm3_lds structure) ----------------
__global__ __launch_bounds__(256) void outproj_mfma(const ushort_t* __restrict__ o1h,
                                                    const ushort_t* __restrict__ o1l,
                                                    const ushort_t* __restrict__ w2h,
                                                    const ushort_t* __restrict__ w2l,
                                                    ushort_t* __restrict__ o2h, ushort_t* __restrict__ o2l,
                                                    int s0) {
    __shared__ ushort_t sAh[128 * 32], sAl[128 * 32], sBh[128 * 32], sBl[128 * 32];
    const int tid = threadIdx.x;
    const int bm = blockIdx.x * 128, h = blockIdx.y;
    const int w = tid >> 6, lane = tid & 63;
    const int wm = (w >> 1) * 64, wn = (w & 1) * 64;
    const int fr = lane & 15, fk = (lane >> 4) * 8;
    const int srow = tid >> 2, skc = (tid & 3) * 8;
    f32x4 acc[4][4];
    for (int i = 0; i < 4; ++i)
        for (int j = 0; j < 4; ++j) acc[i][j] = f32x4{0.f, 0.f, 0.f, 0.f};
    const ushort_t* pAh0 = o1h + ((size_t)(bm + srow) * 16 + h) * 512 + skc;
    const ushort_t* pAh1 = o1h + ((size_t)(bm + 64 + srow) * 16 + h) * 512 + skc;
    const ushort_t* pAl0 = o1l + ((size_t)(bm + srow) * 16 + h) * 512 + skc;
    const ushort_t* pAl1 = o1l + ((size_t)(bm + 64 + srow) * 16 + h) * 512 + skc;
    const ushort_t* pBh0 = w2h + ((size_t)(h * 128 + srow)) * 512 + skc;
    const ushort_t* pBh1 = w2h + ((size_t)(h * 128 + 64 + srow)) * 512 + skc;
    const ushort_t* pBl0 = w2l + ((size_t)(h * 128 + srow)) * 512 + skc;
    const ushort_t* pBl1 = w2l + ((size_t)(h * 128 + 64 + srow)) * 512 + skc;
    ushort_t* dA0 = &sAh[srow * 32 + skc];
    ushort_t* dA1 = &sAh[(64 + srow) * 32 + skc];
    ushort_t* dAl0 = &sAl[srow * 32 + skc];
    ushort_t* dAl1 = &sAl[(64 + srow) * 32 + skc];
    ushort_t* dB0 = &sBh[srow * 32 + skc];
    ushort_t* dB1 = &sBh[(64 + srow) * 32 + skc];
    ushort_t* dBl0 = &sBl[srow * 32 + skc];
    ushort_t* dBl1 = &sBl[(64 + srow) * 32 + skc];
    for (int k0 = 0; k0 < 512; k0 += 32) {
        __syncthreads();
        async16(pAh0, dA0);  async16(pAh1, dA1);
        async16(pAl0, dAl0); async16(pAl1, dAl1);
        async16(pBh0, dB0);  async16(pBh1, dB1);
        async16(pBl0, dBl0); async16(pBl1, dBl1);
        pAh0 += 32; pAh1 += 32; pAl0 += 32; pAl1 += 32;
        pBh0 += 32; pBh1 += 32; pBl0 += 32; pBl1 += 32;
        __syncthreads();
        short8 ahf[4], alf[4], bhf[4], blf[4];
        for (int i = 0; i < 4; ++i) {
            int ro = (wm + i * 16 + fr) * 32 + fk;
            ahf[i] = *(const short8*)&sAh[ro];
            alf[i] = *(const short8*)&sAl[ro];
        }
        for (int j = 0; j < 4; ++j) {
            int ro = (wn + j * 16 + fr) * 32 + fk;
            bhf[j] = *(const short8*)&sBh[ro];
            blf[j] = *(const short8*)&sBl[ro];
        }
        for (int i = 0; i < 4; ++i)
            for (int j = 0; j < 4; ++j) {
                acc[i][j] = mfma_bf16(ahf[i], bhf[j], acc[i][j]);
                acc[i][j] = mfma_bf16(ahf[i], blf[j], acc[i][j]);
                acc[i][j] = mfma_bf16(alf[i], bhf[j], acc[i][j]);
            }
    }
    const int cr = (lane >> 4) * 4, cc = lane & 15;
    for (int i = 0; i < 4; ++i)
        for (int j = 0; j < 4; ++j)
            for (int r = 0; r < 4; ++r) {
                int srow2 = s0 + bm + wm + i * 16 + cr + r;
                int col = wn + j * 16 + cc;
                size_t addr = (size_t)srow2 * 2048 + h * 128 + col;
                float f = acc[i][j][r];
                unsigned short hv = f2bf(f);
                o2h[addr] = hv;
                o2l[addr] = f2bf(f - bf2f(hv));
            }
}

extern "C" void kernel_launch(void* const* d_in, const int* in_sizes, int n_in,
                              void* d_out, int out_size, void* d_ws, size_t ws_size,
                              hipStream_t stream) {
    const float* x         = (const float*)d_in[0];
    const float* fcos      = (const float*)d_in[2];
    const float* fsin      = (const float*)d_in[3];
    const float* q_a_proj  = (const float*)d_in[5];
    const float* q_a_ln_w  = (const float*)d_in[6];
    const float* q_b_proj  = (const float*)d_in[7];
    const float* kv_a_proj = (const float*)d_in[8];
    const float* kv_a_ln_w = (const float*)d_in[9];
    const float* kv_b      = (const float*)d_in[10];
    const float* o_proj    = (const float*)d_in[11];
    const float* idx_wq_b  = (const float*)d_in[12];
    const float* idx_wk    = (const float*)d_in[13];
    const float* iknw      = (const float*)d_in[14];
    const float* iknb      = (const float*)d_in[15];
    const float* idx_wp    = (const float*)d_in[16];
    float* out = (float*)d_out;

    char* ws = (char*)d_ws;
    size_t off = 0;
    auto alloc = [&](size_t bytes) {
        char* p = ws + off;
        off += (bytes + 255) & ~(size_t)255;
        return p;
    };
    // ---- Region A (mostly dead by attention-chunk phase; chunk scratch overlays first 80 MiB) ----
    float* xp  = (float*)alloc((size_t)S * XPLD * 4);     // 17.6 MB
    ushort_t* qrh = (ushort_t*)alloc((size_t)S * Q_LORA * 2);  // 6 MB
    ushort_t* qrl = (ushort_t*)alloc((size_t)S * Q_LORA * 2);  // 6 MB
    float* qib = (float*)alloc((size_t)S * QLD * 4);      // 40 MB: [q 3072 | iqf 2048]
    char* RAt  = alloc(31457280);                         // 30 MiB overlay region (abs 69.6..99.6 MiB)
    float* isc = (float*)RAt;                             // 16.8 MB (dead after topk)
    bf16* iqr  = (bf16*)(RAt + 16777216);                 // 8.4 MB (dead after iscore)
    bf16* ikr  = (bf16*)(RAt + 16777216 + 8388608);       // 0.5 MB (dead after iscore)
    ushort_t* xh = (ushort_t*)RAt;                        // x split (dead after GEMM1)
    ushort_t* xl = xh + (size_t)S * DIM;
    ushort_t* wq2h = (ushort_t*)RAt;                      // q_b|idx_wq_b split (written after GEMM1)
    ushort_t* wq2l = wq2h + (size_t)5120 * Q_LORA;
    float* w1t = (float*)RAt;                             // 4.2 MB (written after topk reads isc)
    ushort_t* wpackh = (ushort_t*)qib;                    // x-proj B split (dead before qib written)
    ushort_t* wpackl = wpackh + (size_t)XPLD_PAD * DIM;
    // RAt tail (abs 91.6..99.6 MiB, beyond the 80 MiB chunk scratch): survives chunk phase.
    char* kvtail = RAt + (size_t)22 * 1024 * 1024;
    unsigned int* kvi = (unsigned int*)kvtail;                       // 4 MiB packed {hi,lo} V
    ushort_t* w2h = (ushort_t*)(kvtail + (size_t)4 * 1024 * 1024);   // 2 MiB
    ushort_t* w2l = w2h + (size_t)16 * 128 * 512;                    // 2 MiB
    // pad region A to cover chunk scratch (scb 32MiB + pbh 16 + pbl 16 + o1h/l 16 = 80 MiB)
    const size_t CHUNK_BYTES = (size_t)SCHUNK * 16 * 1024 * 4 + (size_t)SCHUNK * 16 * 1024 * 2 * 2
                             + (size_t)SCHUNK * 16 * 512 * 4;
    if (off < CHUNK_BYTES) off = (CHUNK_BYTES + 255) & ~(size_t)255;
    // ---- Persistent ----
    int* tk        = (int*)alloc((size_t)S * 1024 * 4);
    float* kv      = (float*)alloc((size_t)S * KV_LORA * 4);
    ushort_t* o2h  = (ushort_t*)alloc((size_t)S * 2048 * 2);
    ushort_t* o2l  = (ushort_t*)alloc((size_t)S * 2048 * 2);
    ushort_t* qah  = (ushort_t*)alloc((size_t)S * 16 * 576 * 2);
    ushort_t* qal  = (ushort_t*)alloc((size_t)S * 16 * 576 * 2);
    ushort_t* kvh  = (ushort_t*)alloc((size_t)S * 576 * 2);
    ushort_t* kvl  = (ushort_t*)alloc((size_t)S * 576 * 2);
    // ---- Chunk-phase aliases over region A ----
    float* scb    = (float*)ws;
    ushort_t* pbh = (ushort_t*)(ws + (size_t)SCHUNK * 16 * 1024 * 4);
    ushort_t* pbl = pbh + (size_t)SCHUNK * 16 * 1024;
    ushort_t* o1h = (ushort_t*)(ws + (size_t)SCHUNK * 16 * 1024 * 8);
    ushort_t* o1l = o1h + (size_t)SCHUNK * 16 * 512;
    // ---- Final-GEMM aliases over scb region (dead after chunk loop) ----
    ushort_t* oph = (ushort_t*)ws;                        // 8.4 MB (o_proj split)
    ushort_t* opl = oph + (size_t)DIM * 2048;             // 8.4 MB

    // ---- split x and the packed x-proj weight [q_a | kv_a | idx_wk | idx_wp] to bf16 hi/lo ----
    split_kernel<<<S * DIM / 1024, 256, 0, stream>>>(x, xh, xl, S * DIM / 4);
    split_kernel<<<Q_LORA * DIM / 1024, 256, 0, stream>>>(q_a_proj, wpackh, wpackl, Q_LORA * DIM / 4);
    split_kernel<<<576 * DIM / 1024, 256, 0, stream>>>(kv_a_proj, wpackh + (size_t)1536 * DIM,
                                                       wpackl + (size_t)1536 * DIM, 576 * DIM / 4);
    split_kernel<<<128 * DIM / 1024, 256, 0, stream>>>(idx_wk, wpackh + (size_t)2112 * DIM,
                                                       wpackl + (size_t)2112 * DIM, 128 * DIM / 4);
    split_kernel<<<16 * DIM / 1024, 256, 0, stream>>>(idx_wp, wpackh + (size_t)2240 * DIM,
                                                      wpackl + (size_t)2240 * DIM, 16 * DIM / 4);
    hipMemsetAsync(wpackh + (size_t)XPLD * DIM, 0, (size_t)(XPLD_PAD - XPLD) * DIM * 2, stream);
    hipMemsetAsync(wpackl + (size_t)XPLD * DIM, 0, (size_t)(XPLD_PAD - XPLD) * DIM * 2, stream);
    // ---- fused x-projection: one GEMM N=2256 (grid padded to 2304) ----
    gemm3_lds<<<dim3((XPLD + 127) / 128, S / 128), 256, 0, stream>>>(xh, xl, wpackh, wpackl, xp, S, XPLD, DIM);
    rms_split_kernel<<<S, 256, 0, stream>>>(xp, qrh, qrl, q_a_ln_w, Q_LORA, XPLD);
    rms_kernel<<<S, 256, 0, stream>>>(xp + 1536, kv, kv_a_ln_w, KV_LORA, XPLD, KV_LORA);
    // ---- fused qr-projection: wq2 = [q_b | idx_wq_b] split (overwrites xh/xl region, dead) ----
    split_kernel<<<3072 * Q_LORA / 1024, 256, 0, stream>>>(q_b_proj, wq2h, wq2l, 3072 * Q_LORA / 4);
    split_kernel<<<2048 * Q_LORA / 1024, 256, 0, stream>>>(idx_wq_b, wq2h + (size_t)3072 * Q_LORA,
                                                           wq2l + (size_t)3072 * Q_LORA, 2048 * Q_LORA / 4);
    gemm3_lds<<<dim3(QLD / 128, S / 128), 256, 0, stream>>>(qrh, qrl, wq2h, wq2l, qib, S, QLD, Q_LORA);
    // ---- rope ----
    rope_inter_kernel<<<S * NH * 32 / 256, 256, 0, stream>>>(qib, fcos, fsin, NH, QK_HD, QK_NOPE, QLD);
    rope_inter_kernel<<<S * 32 / 256, 256, 0, stream>>>(xp + 1536, fcos, fsin, 1, 0, KV_LORA, XPLD);
    // iq rope/rotate/wq only for s >= 1024 (iscore never reads query rows s < 1024: dense-causal there)
    rope_half_kernel<<<S * NH * 32 / 512, 256, 0, stream>>>(qib + 3072, fcos, fsin, NH, 128, QLD, 1024);
    // ---- indexer ----
    ln_kernel<<<S, 128, 0, stream>>>(xp + 2112, iknw, iknb, XPLD);
    rope_half_kernel<<<S * 32 / 256, 256, 0, stream>>>(xp + 2112, fcos, fsin, 1, 0, XPLD, 0);
    rotate_kernel<<<S * NH / 2, 128, 0, stream>>>(qib + 3072, QLD, NH, iqr, 1024 * NH);
    rotate_kernel<<<S, 128, 0, stream>>>(xp + 2112, XPLD, 1, ikr, 0);
    wq_kernel<<<S * NH * 128 / 512, 256, 0, stream>>>(xp + 2240, iqr, 1024 * NH * 128);
    iscore_mfma<<<dim3(16, 8), 256, 0, stream>>>(iqr, ikr, isc);
    topk_kernel<<<1024, 256, 0, stream>>>(isc, tk, 1024);
    // ---- attention prep (kvsplit/splitw2 after iscore: their buffers overlay iqr/ikr) ----
    w1t_kernel<<<dim3(8, 2, 16), 256, 0, stream>>>(kv_b, w1t);
    qabs_mfma<<<dim3(4, S / 128, 16), 256, 0, stream>>>(qib, w1t, qah, qal);
    qpe_split<<<S * NH * 64 / 256, 256, 0, stream>>>(qib, qah, qal);
    kvsplit_kernel<<<S, 576, 0, stream>>>(kv, xp + 1536, kvh, kvl, kvi);
    splitw2_kernel<<<1024, 256, 0, stream>>>(kv_b, w2h, w2l);
    // ---- attention chunks (c<2: s<1024 -> dense mode, no gather) ----
    for (int c = 0; c < 4; ++c) {
        int s0 = c * SCHUNK;
        int dense = (c < 2) ? 1 : 0;
        attn_score_mfma<<<dim3(SCHUNK, 4), 512, 0, stream>>>(qah, qal, kvh, kvl, tk, scb, s0, dense);
        softmax_pb<<<SCHUNK * 16, 256, 0, stream>>>(scb, pbh, pbl);
        attn_pv_mfma<<<SCHUNK, 512, 0, stream>>>(pbh, pbl, kvi, tk, o1h, o1l, s0, dense);
        outproj_mfma<<<dim3(4, 16), 256, 0, stream>>>(o1h, o1l, w2h, w2l, o2h, o2l, s0);
    }
    // ---- final projection: split o_proj into dead scb region, then pure-bf16x3 GEMM ----
    split_kernel<<<DIM * 2048 / 1024, 256, 0, stream>>>(o_proj, oph, opl, DIM * 2048 / 4);
    gemm3_lds<<<dim3(DIM / 128, S / 128), 256, 0, stream>>>(o2h, o2l, oph, opl, out, S, DIM, NH * V_HD);
}

// Round 7
// 1512.483 us; speedup vs baseline: 1.1047x; 1.0018x over previous
//
#include <hip/hip_runtime.h>
#include <hip/hip_bf16.h>
#include <math.h>

#define S 2048
#define NH 16
#define DIM 2048
#define QK_NOPE 128
#define QK_ROPE 64
#define QK_HD 192
#define V_HD 128
#define Q_LORA 1536
#define KV_LORA 512
#define IDX_HD 128
#define SM_SCALE 0.07216878364870323f
#define SCHUNK 512
#define PADK 40
#define XPLD 2256   // packed x-proj output row stride: [qr 1536 | kvp 576 | ikf 128 | iw 16]
#define QLD 5120    // packed qr-proj output row stride: [q 3072 | iqf 2048]
#define XPLD_PAD 2304  // B rows padded to 128 multiple for the x-proj GEMM

typedef __hip_bfloat16 bf16;
typedef unsigned short ushort_t;
typedef __attribute__((ext_vector_type(8))) short short8;
typedef __attribute__((ext_vector_type(4))) float f32x4;

__device__ __forceinline__ f32x4 mfma_bf16(short8 a, short8 b, f32x4 c) {
    return __builtin_amdgcn_mfma_f32_16x16x32_bf16(a, b, c, 0, 0, 0);
}
__device__ __forceinline__ void async16(const void* g, void* l) {
    __builtin_amdgcn_global_load_lds((const __attribute__((address_space(1))) void*)g,
                                     (__attribute__((address_space(3))) void*)l, 16, 0, 0);
}
__device__ __forceinline__ unsigned short f2bf(float f) {  // RNE
    unsigned int u = __float_as_uint(f);
    return (unsigned short)((u + 0x7fff + ((u >> 16) & 1)) >> 16);
}
__device__ __forceinline__ float bf2f(unsigned short b) {
    return __uint_as_float(((unsigned int)b) << 16);
}

// ---------------- fp32 -> bf16 hi/lo split (packed, n4 = elems/4) ----------------
__global__ __launch_bounds__(256) void split_kernel(const float* __restrict__ in, ushort_t* __restrict__ hi,
                                                    ushort_t* __restrict__ lo, int n4) {
    int idx = blockIdx.x * 256 + threadIdx.x;
    if (idx >= n4) return;
    float4 v = ((const float4*)in)[idx];
    ushort4 h, l;
    h.x = f2bf(v.x); l.x = f2bf(v.x - bf2f(h.x));
    h.y = f2bf(v.y); l.y = f2bf(v.y - bf2f(h.y));
    h.z = f2bf(v.z); l.z = f2bf(v.z - bf2f(h.z));
    h.w = f2bf(v.w); l.w = f2bf(v.w - bf2f(h.w));
    ((ushort4*)hi)[idx] = h;
    ((ushort4*)lo)[idx] = l;
}

// ---------------- strided split of kv_b V-half: w2[h][128][512] <- kv_b[h*256+128+r][512] ----------------
__global__ __launch_bounds__(256) void splitw2_kernel(const float* __restrict__ kv_b,
                                                      ushort_t* __restrict__ w2h, ushort_t* __restrict__ w2l) {
    int idx = blockIdx.x * 256 + threadIdx.x;       // 262144 quads
    int h = idx >> 14, rem = idx & 16383;
    int row = rem >> 7, c4 = (rem & 127) * 4;
    float4 v = *(const float4*)(kv_b + ((size_t)(h * 256 + 128 + row)) * 512 + c4);
    ushort4 hh, ll;
    hh.x = f2bf(v.x); ll.x = f2bf(v.x - bf2f(hh.x));
    hh.y = f2bf(v.y); ll.y = f2bf(v.y - bf2f(hh.y));
    hh.z = f2bf(v.z); ll.z = f2bf(v.z - bf2f(hh.z));
    hh.w = f2bf(v.w); ll.w = f2bf(v.w - bf2f(hh.w));
    *(ushort4*)(w2h + ((size_t)(h * 128 + row)) * 512 + c4) = hh;
    *(ushort4*)(w2l + ((size_t)(h * 128 + row)) * 512 + c4) = ll;
}

// ---------------- pre-split bf16x3 MFMA GEMM: C[M,N] = (Ah+Al)[M,K] @ (Bh+Bl)[N,K]^T ----------------
__global__ __launch_bounds__(256) void gemm3_lds(const ushort_t* __restrict__ Ah, const ushort_t* __restrict__ Al,
                                                 const ushort_t* __restrict__ Bh, const ushort_t* __restrict__ Bl,
                                                 float* __restrict__ C, int M, int N, int K) {
    __shared__ ushort_t sAh[128 * 32], sAl[128 * 32], sBh[128 * 32], sBl[128 * 32];
    const int tid = threadIdx.x;
    const int bm = blockIdx.y * 128, bn = blockIdx.x * 128;
    const int w = tid >> 6, lane = tid & 63;
    const int wm = (w >> 1) * 64, wn = (w & 1) * 64;
    const int fr = lane & 15, fk = (lane >> 4) * 8;
    const int srow = tid >> 2, skc = (tid & 3) * 8;
    f32x4 acc[4][4];
    for (int i = 0; i < 4; ++i)
        for (int j = 0; j < 4; ++j) acc[i][j] = f32x4{0.f, 0.f, 0.f, 0.f};
    const ushort_t* pAh0 = Ah + (size_t)(bm + srow) * K + skc;
    const ushort_t* pAh1 = Ah + (size_t)(bm + 64 + srow) * K + skc;
    const ushort_t* pAl0 = Al + (size_t)(bm + srow) * K + skc;
    const ushort_t* pAl1 = Al + (size_t)(bm + 64 + srow) * K + skc;
    const ushort_t* pBh0 = Bh + (size_t)(bn + srow) * K + skc;
    const ushort_t* pBh1 = Bh + (size_t)(bn + 64 + srow) * K + skc;
    const ushort_t* pBl0 = Bl + (size_t)(bn + srow) * K + skc;
    const ushort_t* pBl1 = Bl + (size_t)(bn + 64 + srow) * K + skc;
    ushort_t* dA0 = &sAh[srow * 32 + skc];
    ushort_t* dA1 = &sAh[(64 + srow) * 32 + skc];
    ushort_t* dAl0 = &sAl[srow * 32 + skc];
    ushort_t* dAl1 = &sAl[(64 + srow) * 32 + skc];
    ushort_t* dB0 = &sBh[srow * 32 + skc];
    ushort_t* dB1 = &sBh[(64 + srow) * 32 + skc];
    ushort_t* dBl0 = &sBl[srow * 32 + skc];
    ushort_t* dBl1 = &sBl[(64 + srow) * 32 + skc];
    for (int k0 = 0; k0 < K; k0 += 32) {
        __syncthreads();
        async16(pAh0, dA0);  async16(pAh1, dA1);
        async16(pAl0, dAl0); async16(pAl1, dAl1);
        async16(pBh0, dB0);  async16(pBh1, dB1);
        async16(pBl0, dBl0); async16(pBl1, dBl1);
        pAh0 += 32; pAh1 += 32; pAl0 += 32; pAl1 += 32;
        pBh0 += 32; pBh1 += 32; pBl0 += 32; pBl1 += 32;
        __syncthreads();
        short8 ahf[4], alf[4], bhf[4], blf[4];
        for (int i = 0; i < 4; ++i) {
            int ro = (wm + i * 16 + fr) * 32 + fk;
            ahf[i] = *(const short8*)&sAh[ro];
            alf[i] = *(const short8*)&sAl[ro];
        }
        for (int j = 0; j < 4; ++j) {
            int ro = (wn + j * 16 + fr) * 32 + fk;
            bhf[j] = *(const short8*)&sBh[ro];
            blf[j] = *(const short8*)&sBl[ro];
        }
        for (int i = 0; i < 4; ++i)
            for (int j = 0; j < 4; ++j) {
                acc[i][j] = mfma_bf16(ahf[i], bhf[j], acc[i][j]);
                acc[i][j] = mfma_bf16(ahf[i], blf[j], acc[i][j]);
                acc[i][j] = mfma_bf16(alf[i], bhf[j], acc[i][j]);
            }
    }
    const int cr = (lane >> 4) * 4, cc = lane & 15;
    for (int i = 0; i < 4; ++i)
        for (int j = 0; j < 4; ++j) {
            int row = bm + wm + i * 16 + cr;
            int col = bn + wn + j * 16 + cc;
            if (col < N)
                for (int r = 0; r < 4; ++r)
                    C[(size_t)(row + r) * N + col] = acc[i][j][r];
        }
}

// ---------------- RMSNorm (strided in, fp32 out) ----------------
__global__ __launch_bounds__(256) void rms_kernel(const float* __restrict__ in, float* __restrict__ out,
                                                  const float* __restrict__ w, int C, int ldin, int ldout) {
    const int row = blockIdx.x;
    const float* xr = in + (size_t)row * ldin;
    float* yr = out + (size_t)row * ldout;
    float ss = 0.f;
    for (int c = threadIdx.x; c < C; c += 256) { float v = xr[c]; ss += v * v; }
    for (int o = 32; o; o >>= 1) ss += __shfl_down(ss, o, 64);
    __shared__ float red[4];
    const int wave = threadIdx.x >> 6, lane = threadIdx.x & 63;
    if (lane == 0) red[wave] = ss;
    __syncthreads();
    const float tot = red[0] + red[1] + red[2] + red[3];
    const float scale = rsqrtf(tot / (float)C + 1e-6f);
    for (int c = threadIdx.x; c < C; c += 256) yr[c] = w[c] * (xr[c] * scale);
}

// ---------------- RMSNorm (strided in, bf16 hi/lo packed out) ----------------
__global__ __launch_bounds__(256) void rms_split_kernel(const float* __restrict__ in, ushort_t* __restrict__ hi,
                                                        ushort_t* __restrict__ lo, const float* __restrict__ w,
                                                        int C, int ldin) {
    const int row = blockIdx.x;
    const float* xr = in + (size_t)row * ldin;
    float ss = 0.f;
    for (int c = threadIdx.x; c < C; c += 256) { float v = xr[c]; ss += v * v; }
    for (int o = 32; o; o >>= 1) ss += __shfl_down(ss, o, 64);
    __shared__ float red[4];
    const int wave = threadIdx.x >> 6, lane = threadIdx.x & 63;
    if (lane == 0) red[wave] = ss;
    __syncthreads();
    const float tot = red[0] + red[1] + red[2] + red[3];
    const float scale = rsqrtf(tot / (float)C + 1e-6f);
    for (int c = threadIdx.x; c < C; c += 256) {
        float v = w[c] * (xr[c] * scale);
        unsigned short h = f2bf(v);
        hi[(size_t)row * C + c] = h;
        lo[(size_t)row * C + c] = f2bf(v - bf2f(h));
    }
}

// ---------------- LayerNorm row length 128 (strided, in place) ----------------
__global__ __launch_bounds__(128) void ln_kernel(float* __restrict__ x, const float* __restrict__ w,
                                                 const float* __restrict__ b, int ld) {
    const int row = blockIdx.x;
    float* xr = x + (size_t)row * ld;
    const int tid = threadIdx.x;
    float v = xr[tid];
    float sm = v;
    for (int o = 32; o; o >>= 1) sm += __shfl_down(sm, o, 64);
    __shared__ float red[2];
    if ((tid & 63) == 0) red[tid >> 6] = sm;
    __syncthreads();
    const float mu = (red[0] + red[1]) * (1.f / 128.f);
    __syncthreads();
    float d = v - mu;
    float sv = d * d;
    for (int o = 32; o; o >>= 1) sv += __shfl_down(sv, o, 64);
    if ((tid & 63) == 0) red[tid >> 6] = sv;
    __syncthreads();
    const float var = (red[0] + red[1]) * (1.f / 128.f);
    const float rs = rsqrtf(var + 1e-6f);
    xr[tid] = (v - mu) * rs * w[tid] + b[tid];
}

// ---------------- RoPE interleaved: p = X + s*ld + h*hs + off ----------------
__global__ __launch_bounds__(256) void rope_inter_kernel(float* __restrict__ X, const float* __restrict__ ct,
                                                         const float* __restrict__ st, int H, int hs, int off,
                                                         int ld) {
    int idx = blockIdx.x * 256 + threadIdx.x;
    int k = idx & 31;
    int h = (idx >> 5) % H;
    int s = idx / (32 * H);
    if (s >= S) return;
    float c = ct[s * 32 + k], sn = st[s * 32 + k];
    float* p = X + (size_t)s * ld + h * hs + off;
    float x1 = p[2 * k], x2 = p[2 * k + 1];
    p[2 * k]     = x1 * c - x2 * sn;
    p[2 * k + 1] = x1 * sn + x2 * c;
}

// ---------------- RoPE half: p = X + s*ld + h*hs; soff = first query row ----------------
__global__ __launch_bounds__(256) void rope_half_kernel(float* __restrict__ X, const float* __restrict__ ct,
                                                        const float* __restrict__ st, int H, int hs, int ld,
                                                        int soff) {
    int idx = blockIdx.x * 256 + threadIdx.x;
    int k = idx & 31;
    int h = (idx >> 5) % H;
    int s = idx / (32 * H) + soff;
    if (s >= S) return;
    float c = ct[s * 32 + k], sn = st[s * 32 + k];
    float* p = X + (size_t)s * ld + h * hs;
    float x1 = p[k], x2 = p[32 + k];
    p[k]      = x1 * c - x2 * sn;
    p[32 + k] = x1 * sn + x2 * c;
}

// ---------------- Hadamard rotate: in strided (s*lds + h*128), out packed r*128; roff = first (s,h) ----------------
__global__ __launch_bounds__(128) void rotate_kernel(const float* __restrict__ in, int lds, int H,
                                                     bf16* __restrict__ out, int roff) {
    __shared__ float xs[128];
    const int r = blockIdx.x + roff, j = threadIdx.x;
    const int s = r / H, h = r - s * H;
    float v = in[(size_t)s * lds + h * 128 + j];
    xs[j] = __bfloat162float(__float2bfloat16(v));
    __syncthreads();
    float acc = 0.f;
    for (int d = 0; d < 128; ++d) {
        float xv = xs[d];
        acc += (__popc(d & j) & 1) ? -xv : xv;
    }
    float t = __bfloat162float(__float2bfloat16(acc)) * 0.08838834764831845f;
    out[(size_t)r * 128 + j] = __float2bfloat16(t);
}

// ---------------- wq scale: iw read from strided xp slice; 0.25 folded here; ioff = first element ----------------
__global__ __launch_bounds__(256) void wq_kernel(const float* __restrict__ iwb, bf16* __restrict__ iqr,
                                                 int ioff) {
    int idx = blockIdx.x * 256 + threadIdx.x + ioff;
    int s = idx >> 11, h = (idx >> 7) & 15;
    float a = 0.25f * iwb[(size_t)s * XPLD + h];
    float v = __bfloat162float(iqr[idx]);
    float t = (a * v) * 0.08838834764831845f;
    iqr[idx] = __float2bfloat16(t);
}

// ---------------- index score via bf16 MFMA — only query rows s >= 1024 (s < 1024 never read) ----------------
__global__ __launch_bounds__(256) void iscore_mfma(const bf16* __restrict__ wq, const bf16* __restrict__ ik,
                                                   float* __restrict__ out) {
    if (blockIdx.x > blockIdx.y + 8) return;
    __shared__ unsigned short As[128 * 32], Bs[128 * 32];
    const int bs = (blockIdx.y + 8) * 128, bt = blockIdx.x * 128;
    const int tid = threadIdx.x, w = tid >> 6, lane = tid & 63;
    const int wm = (w >> 1) * 64, wn = (w & 1) * 64;
    const int fr = lane & 15, fk = (lane >> 4) * 8;
    const int srow = lane >> 2, skc = (lane & 3) * 8;
    f32x4 sum[4][4];
    for (int i = 0; i < 4; ++i)
        for (int j = 0; j < 4; ++j) sum[i][j] = f32x4{0.f, 0.f, 0.f, 0.f};
    for (int h = 0; h < 16; ++h) {
        f32x4 acc[4][4];
        for (int i = 0; i < 4; ++i)
            for (int j = 0; j < 4; ++j) acc[i][j] = f32x4{0.f, 0.f, 0.f, 0.f};
        for (int k0 = 0; k0 < 128; k0 += 32) {
            __syncthreads();
            for (int i = 0; i < 2; ++i) {
                int seg = i * 4 + w;
                async16(wq + (size_t)(bs + seg * 16 + srow) * 2048 + h * 128 + k0 + skc, &As[seg * 512]);
                async16(ik + (size_t)(bt + seg * 16 + srow) * 128 + k0 + skc, &Bs[seg * 512]);
            }
            __syncthreads();
            short8 af[4], bff[4];
            for (int i = 0; i < 4; ++i) af[i]  = *(const short8*)&As[(wm + i * 16 + fr) * 32 + fk];
            for (int j = 0; j < 4; ++j) bff[j] = *(const short8*)&Bs[(wn + j * 16 + fr) * 32 + fk];
            for (int i = 0; i < 4; ++i)
                for (int j = 0; j < 4; ++j)
                    acc[i][j] = mfma_bf16(af[i], bff[j], acc[i][j]);
        }
        for (int i = 0; i < 4; ++i)
            for (int j = 0; j < 4; ++j)
                for (int r = 0; r < 4; ++r)
                    sum[i][j][r] += fmaxf(acc[i][j][r], 0.f);
    }
    const int cr = (lane >> 4) * 4, cc = lane & 15;
    for (int i = 0; i < 4; ++i)
        for (int j = 0; j < 4; ++j)
            for (int r = 0; r < 4; ++r)
                out[(size_t)(bs + wm + i * 16 + cr + r) * 2048 + bt + wn + j * 16 + cc] = sum[i][j][r];
}

// ---------------- top-k (launched only for s >= s0 = 1024; s < 1024 is dense-causal, tk unused) ----------------
__global__ __launch_bounds__(256) void topk_kernel(const float* __restrict__ isc, int* __restrict__ tk,
                                                   int s0) {
    __shared__ unsigned long long keys[2048];
    const int s = s0 + blockIdx.x;
    const float* row = isc + (size_t)s * 2048;
    for (int t = threadIdx.x; t < 2048; t += 256) {
        unsigned long long kk = 0ull;
        if (t <= s) {
            unsigned int vb = __float_as_uint(row[t]);
            kk = ((unsigned long long)vb << 32) | (unsigned int)(2048 - t);
        }
        keys[t] = kk;
    }
    __syncthreads();
    for (int k = 2; k <= 2048; k <<= 1) {
        for (int j = k >> 1; j > 0; j >>= 1) {
            for (int t = threadIdx.x; t < 2048; t += 256) {
                int l = t ^ j;
                if (l > t) {
                    bool up = ((t & k) == 0);
                    unsigned long long a = keys[t], b = keys[l];
                    bool sw = up ? (a < b) : (a > b);
                    if (sw) { keys[t] = b; keys[l] = a; }
                }
            }
            __syncthreads();
        }
    }
    const int cnt = min(1024, s + 1);
    for (int i = threadIdx.x; i < 1024; i += 256) {
        int t = (i < cnt) ? (2048 - (int)(keys[i] & 0xFFFFFFFFull)) : -1;
        tk[(size_t)s * 1024 + i] = t;
    }
}

// ---------------- transpose kv_b head-1 part ----------------
__global__ __launch_bounds__(256) void w1t_kernel(const float* __restrict__ kv_b, float* __restrict__ w1t) {
    __shared__ float ts[64][65];
    const int cb = blockIdx.x * 64, db = blockIdx.y * 64, h = blockIdx.z;
    const int t = threadIdx.x;
    for (int it = 0; it < 16; ++it) {
        int idx = it * 256 + t;
        int rr = idx >> 6, cc = idx & 63;
        ts[rr][cc] = kv_b[(size_t)(h * 256 + db + rr) * 512 + cb + cc];
    }
    __syncthreads();
    for (int it = 0; it < 16; ++it) {
        int idx = it * 256 + t;
        int rr = idx >> 6, cc = idx & 63;
        w1t[(size_t)h * 65536 + (size_t)(cb + rr) * 128 + db + cc] = ts[cc][rr];
    }
}

// ---------------- kv split: hi/lo rows of 576 for score; packed u32 {hi,lo} V rows for pv ----------------
__global__ __launch_bounds__(576) void kvsplit_kernel(const float* __restrict__ kv, const float* __restrict__ kpe,
                                                      ushort_t* __restrict__ kvh, ushort_t* __restrict__ kvl,
                                                      unsigned int* __restrict__ kvi) {
    const int t = blockIdx.x, c = threadIdx.x;
    float v = (c < 512) ? kv[(size_t)t * 512 + c] : kpe[(size_t)t * XPLD + c];
    unsigned short hi = f2bf(v);
    unsigned short lo = f2bf(v - bf2f(hi));
    kvh[(size_t)t * 576 + c] = hi;
    kvl[(size_t)t * 576 + c] = lo;
    if (c < 512) kvi[(size_t)t * 512 + c] = (unsigned int)hi | ((unsigned int)lo << 16);
}

// ---------------- qabs via bf16x3 MFMA (q strided from packed qib) ----------------
__global__ __launch_bounds__(256) void qabs_mfma(const float* __restrict__ q, const float* __restrict__ w1t,
                                                 ushort_t* __restrict__ qah, ushort_t* __restrict__ qal) {
    __shared__ unsigned short Ah[128 * PADK], Al[128 * PADK], Bh[128 * PADK], Bl[128 * PADK];
    const int tid = threadIdx.x;
    const int bn = blockIdx.x * 128, bm = blockIdx.y * 128, h = blockIdx.z;
    const int w = tid >> 6, lane = tid & 63;
    const int wm = (w >> 1) * 64, wn = (w & 1) * 64;
    const int fr = lane & 15, fk = (lane >> 4) * 8;
    f32x4 acc[4][4];
    for (int i = 0; i < 4; ++i)
        for (int j = 0; j < 4; ++j) acc[i][j] = f32x4{0.f, 0.f, 0.f, 0.f};
    for (int k0 = 0; k0 < 128; k0 += 32) {
        __syncthreads();
        for (int it = 0; it < 4; ++it) {
            int f = it * 256 + tid;
            int row = f >> 3, kc = (f & 7) * 4;
            float4 av = *(const float4*)(q + (size_t)(bm + row) * QLD + h * QK_HD + k0 + kc);
            float4 bv = *(const float4*)(w1t + (size_t)h * 65536 + (size_t)(bn + row) * 128 + k0 + kc);
            ushort4 ahi, alo, bhi, blo;
            ahi.x = f2bf(av.x); alo.x = f2bf(av.x - bf2f(ahi.x));
            ahi.y = f2bf(av.y); alo.y = f2bf(av.y - bf2f(ahi.y));
            ahi.z = f2bf(av.z); alo.z = f2bf(av.z - bf2f(ahi.z));
            ahi.w = f2bf(av.w); alo.w = f2bf(av.w - bf2f(ahi.w));
            bhi.x = f2bf(bv.x); blo.x = f2bf(bv.x - bf2f(bhi.x));
            bhi.y = f2bf(bv.y); blo.y = f2bf(bv.y - bf2f(bhi.y));
            bhi.z = f2bf(bv.z); blo.z = f2bf(bv.z - bf2f(bhi.z));
            bhi.w = f2bf(bv.w); blo.w = f2bf(bv.w - bf2f(bhi.w));
            *(ushort4*)&Ah[row * PADK + kc] = ahi;
            *(ushort4*)&Al[row * PADK + kc] = alo;
            *(ushort4*)&Bh[row * PADK + kc] = bhi;
            *(ushort4*)&Bl[row * PADK + kc] = blo;
        }
        __syncthreads();
        short8 ahf[4], alf[4], bhf[4], blf[4];
        for (int i = 0; i < 4; ++i) {
            int ro = (wm + i * 16 + fr) * PADK + fk;
            ahf[i] = *(const short8*)&Ah[ro];
            alf[i] = *(const short8*)&Al[ro];
        }
        for (int j = 0; j < 4; ++j) {
            int ro = (wn + j * 16 + fr) * PADK + fk;
            bhf[j] = *(const short8*)&Bh[ro];
            blf[j] = *(const short8*)&Bl[ro];
        }
        for (int i = 0; i < 4; ++i)
            for (int j = 0; j < 4; ++j) {
                acc[i][j] = mfma_bf16(ahf[i], bhf[j], acc[i][j]);
                acc[i][j] = mfma_bf16(ahf[i], blf[j], acc[i][j]);
                acc[i][j] = mfma_bf16(alf[i], bhf[j], acc[i][j]);
            }
    }
    const int cr = (lane >> 4) * 4, cc = lane & 15;
    for (int i = 0; i < 4; ++i)
        for (int j = 0; j < 4; ++j)
            for (int r = 0; r < 4; ++r) {
                int srow = bm + wm + i * 16 + cr + r;
                int col = bn + wn + j * 16 + cc;
                float f = acc[i][j][r] * SM_SCALE;
                size_t addr = ((size_t)srow * 16 + h) * 576 + col;
                unsigned short hi = f2bf(f);
                qah[addr] = hi;
                qal[addr] = f2bf(f - bf2f(hi));
            }
}

// ---------------- qpe split (q strided from packed qib) ----------------
__global__ __launch_bounds__(256) void qpe_split(const float* __restrict__ q, ushort_t* __restrict__ qah,
                                                 ushort_t* __restrict__ qal) {
    int idx = blockIdx.x * 256 + threadIdx.x;
    int r = idx & 63, h = (idx >> 6) & 15, s = idx >> 10;
    float f = q[(size_t)s * QLD + h * QK_HD + 128 + r] * SM_SCALE;
    size_t addr = ((size_t)s * 16 + h) * 576 + 512 + r;
    unsigned short hi = f2bf(f);
    qah[addr] = hi;
    qal[addr] = f2bf(f - bf2f(hi));
}

// ---------------- attn_score via MFMA bf16x3 — BARRIER-FREE per-wave pipelines (T3/T4) ----------------
// Round-6 PMC: per-chunk __syncthreads lock-stepped 8 waves at the slowest scattered load; nothing
// saturated (MfmaUtil 8%, L2-fill 1.3 TB/s). Each wave consumes ONLY its own 32 key rows, so: wave
// owns its LDS slice, stages its own rows via global_load_lds, and waits with per-wave counted
// s_waitcnt vmcnt(6) (= 4 stage + 2 q loads of next chunk in flight). Zero __syncthreads -> 16
// independent wave pipelines per CU. LDS addresses/content/MFMA order identical to round 6.
#define SC_STAGE(BUF, O)                                    \
    async16(gha + (O), &kh[BUF][w * 1024]);                 \
    async16(ghb + (O), &kh[BUF][w * 1024 + 512]);           \
    async16(gla + (O), &kl[BUF][w * 1024]);                 \
    async16(glb + (O), &kl[BUF][w * 1024 + 512]);
__global__ __launch_bounds__(512) void attn_score_mfma(const ushort_t* __restrict__ qah,
                                                       const ushort_t* __restrict__ qal,
                                                       const ushort_t* __restrict__ kvh,
                                                       const ushort_t* __restrict__ kvl,
                                                       const int* __restrict__ tk,
                                                       float* __restrict__ scb, int s0, int dense) {
    const int sl = blockIdx.x, s = s0 + sl, pass = blockIdx.y;
    const int tid = threadIdx.x, w = tid >> 6, lane = tid & 63;
    const int cnt = min(1024, s + 1);
    if (pass * 256 >= cnt) {  // whole pass masked: write NEG and exit (no gather)
        for (int i = tid; i < 4096; i += 512) {
            int head = i >> 8, key = i & 255;
            scb[((size_t)sl * 16 + head) * 1024 + pass * 256 + key] = -1e30f;
        }
        return;
    }
    __shared__ __align__(16) ushort_t kh[2][8192], kl[2][8192];
    // per-lane staged rows: wave w owns key slots w*32..w*32+31; lane l stages rows l>>2 and 16+(l>>2)
    const int rloc = lane >> 2;
    int t_a, t_b;
    if (dense) {
        t_a = pass * 256 + w * 32 + rloc;
        t_b = t_a + 16;
    } else {
        int ta = tk[(size_t)s * 1024 + pass * 256 + w * 32 + rloc];
        int tb = tk[(size_t)s * 1024 + pass * 256 + w * 32 + 16 + rloc];
        t_a = ta < 0 ? 0 : ta;
        t_b = tb < 0 ? 0 : tb;
    }
    // granule slot swizzle (involution): slot (l&3) holds global granule (l&3)^((rloc>>1)&3)
    const int swg = (lane & 3) ^ ((lane >> 3) & 3);
    const ushort_t* gha = kvh + (size_t)t_a * 576 + swg * 8;
    const ushort_t* ghb = kvh + (size_t)t_b * 576 + swg * 8;
    const ushort_t* gla = kvl + (size_t)t_a * 576 + swg * 8;
    const ushort_t* glb = kvl + (size_t)t_b * 576 + swg * 8;
    const int fr = lane & 15, g = lane >> 4;
    const size_t abase = ((size_t)s * 16 + fr) * 576 + g * 8;
    // LDS read offsets (shorts): row fr / 16+fr of wave slice, slot g ^ ((fr>>1)&3)
    const int ro0 = w * 1024 + fr * 32 + ((g ^ ((fr >> 1) & 3)) << 3);
    const int ro1 = ro0 + 512;
    f32x4 acc0 = {0.f, 0.f, 0.f, 0.f}, acc1 = {0.f, 0.f, 0.f, 0.f};
    SC_STAGE(0, 0)
    short8 qh = *(const short8*)(qah + abase);
    short8 ql = *(const short8*)(qal + abase);
    for (int ch = 0; ch < 17; ++ch) {
        const int cur = ch & 1;
        SC_STAGE(cur ^ 1, (ch + 1) * 32)
        short8 qhn = *(const short8*)(qah + abase + (ch + 1) * 32);
        short8 qln = *(const short8*)(qal + abase + (ch + 1) * 32);
        asm volatile("s_waitcnt vmcnt(6)" ::: "memory");   // cur's 4 stage loads done; 6 newer in flight
        __builtin_amdgcn_sched_barrier(0);
        short8 bh0 = *(const short8*)&kh[cur][ro0];
        short8 bl0 = *(const short8*)&kl[cur][ro0];
        short8 bh1 = *(const short8*)&kh[cur][ro1];
        short8 bl1 = *(const short8*)&kl[cur][ro1];
        acc0 = mfma_bf16(qh, bh0, acc0);
        acc0 = mfma_bf16(qh, bl0, acc0);
        acc0 = mfma_bf16(ql, bh0, acc0);
        acc1 = mfma_bf16(qh, bh1, acc1);
        acc1 = mfma_bf16(qh, bl1, acc1);
        acc1 = mfma_bf16(ql, bh1, acc1);
        qh = qhn; ql = qln;
    }
    {   // epilogue chunk 17 (buf 1)
        asm volatile("s_waitcnt vmcnt(0)" ::: "memory");
        __builtin_amdgcn_sched_barrier(0);
        short8 bh0 = *(const short8*)&kh[1][ro0];
        short8 bl0 = *(const short8*)&kl[1][ro0];
        short8 bh1 = *(const short8*)&kh[1][ro1];
        short8 bl1 = *(const short8*)&kl[1][ro1];
        acc0 = mfma_bf16(qh, bh0, acc0);
        acc0 = mfma_bf16(qh, bl0, acc0);
        acc0 = mfma_bf16(ql, bh0, acc0);
        acc1 = mfma_bf16(qh, bh1, acc1);
        acc1 = mfma_bf16(qh, bl1, acc1);
        acc1 = mfma_bf16(ql, bh1, acc1);
    }
    const int cr = (lane >> 4) * 4, cc = lane & 15;
    for (int r = 0; r < 4; ++r) {
        int head = cr + r;
        int key0 = pass * 256 + w * 32 + cc;
        int key1 = key0 + 16;
        scb[((size_t)sl * 16 + head) * 1024 + key0] = (key0 < cnt) ? acc0[r] : -1e30f;
        scb[((size_t)sl * 16 + head) * 1024 + key1] = (key1 < cnt) ? acc1[r] : -1e30f;
    }
}

// ---------------- softmax -> p as bf16 hi/lo ----------------
__global__ __launch_bounds__(256) void softmax_pb(const float* __restrict__ scb,
                                                  ushort_t* __restrict__ pbh, ushort_t* __restrict__ pbl) {
    const size_t row = blockIdx.x;
    const float* src = scb + row * 1024;
    const int tid = threadIdx.x, wave = tid >> 6, lane = tid & 63;
    __shared__ float red[4];
    float v[4];
    float m = -INFINITY;
    for (int i = 0; i < 4; ++i) { v[i] = src[tid + 256 * i]; m = fmaxf(m, v[i]); }
    for (int o = 32; o; o >>= 1) m = fmaxf(m, __shfl_down(m, o, 64));
    if (lane == 0) red[wave] = m;
    __syncthreads();
    m = fmaxf(fmaxf(red[0], red[1]), fmaxf(red[2], red[3]));
    __syncthreads();
    float e[4], l = 0.f;
    for (int i = 0; i < 4; ++i) { e[i] = __expf(v[i] - m); l += e[i]; }
    for (int o = 32; o; o >>= 1) l += __shfl_down(l, o, 64);
    if (lane == 0) red[wave] = l;
    __syncthreads();
    const float il = 1.f / (red[0] + red[1] + red[2] + red[3]);
    for (int i = 0; i < 4; ++i) {
        float p = e[i] * il;
        unsigned short hi = f2bf(p);
        pbh[row * 1024 + tid + 256 * i] = hi;
        pbl[row * 1024 + tid + 256 * i] = f2bf(p - bf2f(hi));
    }
}

// ---------------- attn_pv via MFMA bf16x3 — packed {hi,lo} V, NAMED-reg prefetch (rule #20) ----
// dense=1: identity key ordering (see attn_score comment) -> sequential V rows shared across blocks.
#define PV_GATHER(KC)                                                                    \
    g0 = *(const uint4*)(kvi + (size_t)tks[(KC) * 32 + r0     ] * 512 + gp4);            \
    g1 = *(const uint4*)(kvi + (size_t)tks[(KC) * 32 + r0 + 4 ] * 512 + gp4);            \
    g2 = *(const uint4*)(kvi + (size_t)tks[(KC) * 32 + r0 + 8 ] * 512 + gp4);            \
    g3 = *(const uint4*)(kvi + (size_t)tks[(KC) * 32 + r0 + 12] * 512 + gp4);            \
    g4 = *(const uint4*)(kvi + (size_t)tks[(KC) * 32 + r0 + 16] * 512 + gp4);            \
    g5 = *(const uint4*)(kvi + (size_t)tks[(KC) * 32 + r0 + 20] * 512 + gp4);            \
    g6 = *(const uint4*)(kvi + (size_t)tks[(KC) * 32 + r0 + 24] * 512 + gp4);            \
    g7 = *(const uint4*)(kvi + (size_t)tks[(KC) * 32 + r0 + 28] * 512 + gp4);
#define PV_STORE()                                                                       \
    *(uint4*)&vt[(r0     ) * 512 + ((gp ^ 0) << 2)] = g0;                                \
    *(uint4*)&vt[(r0 + 4 ) * 512 + ((gp ^ 0) << 2)] = g1;                                \
    *(uint4*)&vt[(r0 + 8 ) * 512 + ((gp ^ 2) << 2)] = g2;                                \
    *(uint4*)&vt[(r0 + 12) * 512 + ((gp ^ 2) << 2)] = g3;                                \
    *(uint4*)&vt[(r0 + 16) * 512 + ((gp ^ 4) << 2)] = g4;                                \
    *(uint4*)&vt[(r0 + 20) * 512 + ((gp ^ 4) << 2)] = g5;                                \
    *(uint4*)&vt[(r0 + 24) * 512 + ((gp ^ 6) << 2)] = g6;                                \
    *(uint4*)&vt[(r0 + 28) * 512 + ((gp ^ 6) << 2)] = g7;
__global__ __launch_bounds__(512) void attn_pv_mfma(const ushort_t* __restrict__ pbh,
                                                    const ushort_t* __restrict__ pbl,
                                                    const unsigned int* __restrict__ kvi,
                                                    const int* __restrict__ tk,
                                                    ushort_t* __restrict__ o1h, ushort_t* __restrict__ o1l,
                                                    int s0, int dense) {
    const int sl = blockIdx.x, s = s0 + sl;
    const int tid = threadIdx.x, w = tid >> 6, lane = tid & 63;
    __shared__ int tks[1024];
    __shared__ unsigned int vt[32 * 512];   // 64 KiB
    for (int j = tid; j < 1024; j += 512) {
        if (dense) {
            tks[j] = j;
        } else {
            int t = tk[(size_t)s * 1024 + j];
            tks[j] = t < 0 ? 0 : t;
        }
    }
    const int fr = lane & 15, g = lane >> 4, fko = g * 8;
    const int r0 = tid >> 7;        // 0..3
    const int gp = tid & 127;       // 16B granule column (4 u32)
    const int gp4 = gp * 4;
    f32x4 acc[4];
    for (int i = 0; i < 4; ++i) acc[i] = f32x4{0.f, 0.f, 0.f, 0.f};
    const size_t pbase = ((size_t)sl * 16 + fr) * 1024 + fko;
    uint4 g0, g1, g2, g3, g4, g5, g6, g7;
    __syncthreads();                // tks ready
    PV_GATHER(0)
    PV_STORE()
    __syncthreads();                // vt chunk 0 ready
    for (int kc = 0; kc < 32; ++kc) {
        if (kc < 31) {              // prefetch next chunk into named regs (coalesced 1KB per wave)
            PV_GATHER(kc + 1)
        }
        short8 ph = *(const short8*)(pbh + pbase + kc * 32);
        short8 pl = *(const short8*)(pbl + pbase + kc * 32);
        #pragma unroll
        for (int sub = 0; sub < 4; ++sub) {
            const int cb = (w * 64 + sub * 16 + fr) ^ (g << 3);
            short8 bh, bl;
            #pragma unroll
            for (int jj = 0; jj < 8; ++jj) {
                const unsigned int v = vt[(fko + jj) * 512 + cb];
                bh[jj] = (short)(v & 0xffffu);
                bl[jj] = (short)(v >> 16);
            }
            acc[sub] = mfma_bf16(ph, bh, acc[sub]);
            acc[sub] = mfma_bf16(pl, bh, acc[sub]);
            acc[sub] = mfma_bf16(ph, bl, acc[sub]);
        }
        __syncthreads();            // all waves done reading vt
        if (kc < 31) {
            PV_STORE()
            __syncthreads();        // vt next chunk ready
        }
    }
    const int cr = (lane >> 4) * 4, cc = lane & 15;
    for (int sub = 0; sub < 4; ++sub)
        for (int r = 0; r < 4; ++r) {
            int head = cr + r, c = w * 64 + sub * 16 + cc;
            float f = acc[sub][r];
            unsigned short hv = f2bf(f);
            size_t addr = ((size_t)sl * 16 + head) * 512 + c;
            o1h[addr] = hv;
            o1l[addr] = f2bf(f - bf2f(hv));
        }
}

// ---------------- outproj via pre-split bf16x3 MFMA (gemm3_lds structure) ----------------
__global__ __launch_bounds__(256) void outproj_mfma(const ushort_t* __restrict__ o1h,
                                                    const ushort_t* __restrict__ o1l,
                                                    const ushort_t* __restrict__ w2h,
                                                    const ushort_t* __restrict__ w2l,
                                                    ushort_t* __restrict__ o2h, ushort_t* __restrict__ o2l,
                                                    int s0) {
    __shared__ ushort_t sAh[128 * 32], sAl[128 * 32], sBh[128 * 32], sBl[128 * 32];
    const int tid = threadIdx.x;
    const int bm = blockIdx.x * 128, h = blockIdx.y;
    const int w = tid >> 6, lane = tid & 63;
    const int wm = (w >> 1) * 64, wn = (w & 1) * 64;
    const int fr = lane & 15, fk = (lane >> 4) * 8;
    const int srow = tid >> 2, skc = (tid & 3) * 8;
    f32x4 acc[4][4];
    for (int i = 0; i < 4; ++i)
        for (int j = 0; j < 4; ++j) acc[i][j] = f32x4{0.f, 0.f, 0.f, 0.f};
    const ushort_t* pAh0 = o1h + ((size_t)(bm + srow) * 16 + h) * 512 + skc;
    const ushort_t* pAh1 = o1h + ((size_t)(bm + 64 + srow) * 16 + h) * 512 + skc;
    const ushort_t* pAl0 = o1l + ((size_t)(bm + srow) * 16 + h) * 512 + skc;
    const ushort_t* pAl1 = o1l + ((size_t)(bm + 64 + srow) * 16 + h) * 512 + skc;
    const ushort_t* pBh0 = w2h + ((size_t)(h * 128 + srow)) * 512 + skc;
    const ushort_t* pBh1 = w2h + ((size_t)(h * 128 + 64 + srow)) * 512 + skc;
    const ushort_t* pBl0 = w2l + ((size_t)(h * 128 + srow)) * 512 + skc;
    const ushort_t* pBl1 = w2l + ((size_t)(h * 128 + 64 + srow)) * 512 + skc;
    ushort_t* dA0 = &sAh[srow * 32 + skc];
    ushort_t* dA1 = &sAh[(64 + srow) * 32 + skc];
    ushort_t* dAl0 = &sAl[srow * 32 + skc];
    ushort_t* dAl1 = &sAl[(64 + srow) * 32 + skc];
    ushort_t* dB0 = &sBh[srow * 32 + skc];
    ushort_t* dB1 = &sBh[(64 + srow) * 32 + skc];
    ushort_t* dBl0 = &sBl[srow * 32 + skc];
    ushort_t* dBl1 = &sBl[(64 + srow) * 32 + skc];
    for (int k0 = 0; k0 < 512; k0 += 32) {
        __syncthreads();
        async16(pAh0, dA0);  async16(pAh1, dA1);
        async16(pAl0, dAl0); async16(pAl1, dAl1);
        async16(pBh0, dB0);  async16(pBh1, dB1);
        async16(pBl0, dBl0); async16(pBl1, dBl1);
        pAh0 += 32; pAh1 += 32; pAl0 += 32; pAl1 += 32;
        pBh0 += 32; pBh1 += 32; pBl0 += 32; pBl1 += 32;
        __syncthreads();
        short8 ahf[4], alf[4], bhf[4], blf[4];
        for (int i = 0; i < 4; ++i) {
            int ro = (wm + i * 16 + fr) * 32 + fk;
            ahf[i] = *(const short8*)&sAh[ro];
            alf[i] = *(const short8*)&sAl[ro];
        }
        for (int j = 0; j < 4; ++j) {
            int ro = (wn + j * 16 + fr) * 32 + fk;
            bhf[j] = *(const short8*)&sBh[ro];
            blf[j] = *(const short8*)&sBl[ro];
        }
        for (int i = 0; i < 4; ++i)
            for (int j = 0; j < 4; ++j) {
                acc[i][j] = mfma_bf16(ahf[i], bhf[j], acc[i][j]);
                acc[i][j] = mfma_bf16(ahf[i], blf[j], acc[i][j]);
                acc[i][j] = mfma_bf16(alf[i], bhf[j], acc[i][j]);
            }
    }
    const int cr = (lane >> 4) * 4, cc = lane & 15;
    for (int i = 0; i < 4; ++i)
        for (int j = 0; j < 4; ++j)
            for (int r = 0; r < 4; ++r) {
                int srow2 = s0 + bm + wm + i * 16 + cr + r;
                int col = wn + j * 16 + cc;
                size_t addr = (size_t)srow2 * 2048 + h * 128 + col;
                float f = acc[i][j][r];
                unsigned short hv = f2bf(f);
                o2h[addr] = hv;
                o2l[addr] = f2bf(f - bf2f(hv));
            }
}

extern "C" void kernel_launch(void* const* d_in, const int* in_sizes, int n_in,
                              void* d_out, int out_size, void* d_ws, size_t ws_size,
                              hipStream_t stream) {
    const float* x         = (const float*)d_in[0];
    const float* fcos      = (const float*)d_in[2];
    const float* fsin      = (const float*)d_in[3];
    const float* q_a_proj  = (const float*)d_in[5];
    const float* q_a_ln_w  = (const float*)d_in[6];
    const float* q_b_proj  = (const float*)d_in[7];
    const float* kv_a_proj = (const float*)d_in[8];
    const float* kv_a_ln_w = (const float*)d_in[9];
    const float* kv_b      = (const float*)d_in[10];
    const float* o_proj    = (const float*)d_in[11];
    const float* idx_wq_b  = (const float*)d_in[12];
    const float* idx_wk    = (const float*)d_in[13];
    const float* iknw      = (const float*)d_in[14];
    const float* iknb      = (const float*)d_in[15];
    const float* idx_wp    = (const float*)d_in[16];
    float* out = (float*)d_out;

    char* ws = (char*)d_ws;
    size_t off = 0;
    auto alloc = [&](size_t bytes) {
        char* p = ws + off;
        off += (bytes + 255) & ~(size_t)255;
        return p;
    };
    // ---- Region A (mostly dead by attention-chunk phase; chunk scratch overlays first 80 MiB) ----
    float* xp  = (float*)alloc((size_t)S * XPLD * 4);     // 17.6 MB
    ushort_t* qrh = (ushort_t*)alloc((size_t)S * Q_LORA * 2);  // 6 MB
    ushort_t* qrl = (ushort_t*)alloc((size_t)S * Q_LORA * 2);  // 6 MB
    float* qib = (float*)alloc((size_t)S * QLD * 4);      // 40 MB: [q 3072 | iqf 2048]
    char* RAt  = alloc(31457280);                         // 30 MiB overlay region (abs 69.6..99.6 MiB)
    float* isc = (float*)RAt;                             // 16.8 MB (dead after topk)
    bf16* iqr  = (bf16*)(RAt + 16777216);                 // 8.4 MB (dead after iscore)
    bf16* ikr  = (bf16*)(RAt + 16777216 + 8388608);       // 0.5 MB (dead after iscore)
    ushort_t* xh = (ushort_t*)RAt;                        // x split (dead after GEMM1)
    ushort_t* xl = xh + (size_t)S * DIM;
    ushort_t* wq2h = (ushort_t*)RAt;                      // q_b|idx_wq_b split (written after GEMM1)
    ushort_t* wq2l = wq2h + (size_t)5120 * Q_LORA;
    float* w1t = (float*)RAt;                             // 4.2 MB (written after topk reads isc)
    ushort_t* wpackh = (ushort_t*)qib;                    // x-proj B split (dead before qib written)
    ushort_t* wpackl = wpackh + (size_t)XPLD_PAD * DIM;
    // RAt tail (abs 91.6..99.6 MiB, beyond the 80 MiB chunk scratch): survives chunk phase.
    char* kvtail = RAt + (size_t)22 * 1024 * 1024;
    unsigned int* kvi = (unsigned int*)kvtail;                       // 4 MiB packed {hi,lo} V
    ushort_t* w2h = (ushort_t*)(kvtail + (size_t)4 * 1024 * 1024);   // 2 MiB
    ushort_t* w2l = w2h + (size_t)16 * 128 * 512;                    // 2 MiB
    // pad region A to cover chunk scratch (scb 32MiB + pbh 16 + pbl 16 + o1h/l 16 = 80 MiB)
    const size_t CHUNK_BYTES = (size_t)SCHUNK * 16 * 1024 * 4 + (size_t)SCHUNK * 16 * 1024 * 2 * 2
                             + (size_t)SCHUNK * 16 * 512 * 4;
    if (off < CHUNK_BYTES) off = (CHUNK_BYTES + 255) & ~(size_t)255;
    // ---- Persistent ----
    int* tk        = (int*)alloc((size_t)S * 1024 * 4);
    float* kv      = (float*)alloc((size_t)S * KV_LORA * 4);
    ushort_t* o2h  = (ushort_t*)alloc((size_t)S * 2048 * 2);
    ushort_t* o2l  = (ushort_t*)alloc((size_t)S * 2048 * 2);
    ushort_t* qah  = (ushort_t*)alloc((size_t)S * 16 * 576 * 2);
    ushort_t* qal  = (ushort_t*)alloc((size_t)S * 16 * 576 * 2);
    ushort_t* kvh  = (ushort_t*)alloc((size_t)S * 576 * 2);
    ushort_t* kvl  = (ushort_t*)alloc((size_t)S * 576 * 2);
    // ---- Chunk-phase aliases over region A ----
    float* scb    = (float*)ws;
    ushort_t* pbh = (ushort_t*)(ws + (size_t)SCHUNK * 16 * 1024 * 4);
    ushort_t* pbl = pbh + (size_t)SCHUNK * 16 * 1024;
    ushort_t* o1h = (ushort_t*)(ws + (size_t)SCHUNK * 16 * 1024 * 8);
    ushort_t* o1l = o1h + (size_t)SCHUNK * 16 * 512;
    // ---- Final-GEMM aliases over scb region (dead after chunk loop) ----
    ushort_t* oph = (ushort_t*)ws;                        // 8.4 MB (o_proj split)
    ushort_t* opl = oph + (size_t)DIM * 2048;             // 8.4 MB

    // ---- split x and the packed x-proj weight [q_a | kv_a | idx_wk | idx_wp] to bf16 hi/lo ----
    split_kernel<<<S * DIM / 1024, 256, 0, stream>>>(x, xh, xl, S * DIM / 4);
    split_kernel<<<Q_LORA * DIM / 1024, 256, 0, stream>>>(q_a_proj, wpackh, wpackl, Q_LORA * DIM / 4);
    split_kernel<<<576 * DIM / 1024, 256, 0, stream>>>(kv_a_proj, wpackh + (size_t)1536 * DIM,
                                                       wpackl + (size_t)1536 * DIM, 576 * DIM / 4);
    split_kernel<<<128 * DIM / 1024, 256, 0, stream>>>(idx_wk, wpackh + (size_t)2112 * DIM,
                                                       wpackl + (size_t)2112 * DIM, 128 * DIM / 4);
    split_kernel<<<16 * DIM / 1024, 256, 0, stream>>>(idx_wp, wpackh + (size_t)2240 * DIM,
                                                      wpackl + (size_t)2240 * DIM, 16 * DIM / 4);
    hipMemsetAsync(wpackh + (size_t)XPLD * DIM, 0, (size_t)(XPLD_PAD - XPLD) * DIM * 2, stream);
    hipMemsetAsync(wpackl + (size_t)XPLD * DIM, 0, (size_t)(XPLD_PAD - XPLD) * DIM * 2, stream);
    // ---- fused x-projection: one GEMM N=2256 (grid padded to 2304) ----
    gemm3_lds<<<dim3((XPLD + 127) / 128, S / 128), 256, 0, stream>>>(xh, xl, wpackh, wpackl, xp, S, XPLD, DIM);
    rms_split_kernel<<<S, 256, 0, stream>>>(xp, qrh, qrl, q_a_ln_w, Q_LORA, XPLD);
    rms_kernel<<<S, 256, 0, stream>>>(xp + 1536, kv, kv_a_ln_w, KV_LORA, XPLD, KV_LORA);
    // ---- fused qr-projection: wq2 = [q_b | idx_wq_b] split (overwrites xh/xl region, dead) ----
    split_kernel<<<3072 * Q_LORA / 1024, 256, 0, stream>>>(q_b_proj, wq2h, wq2l, 3072 * Q_LORA / 4);
    split_kernel<<<2048 * Q_LORA / 1024, 256, 0, stream>>>(idx_wq_b, wq2h + (size_t)3072 * Q_LORA,
                                                           wq2l + (size_t)3072 * Q_LORA, 2048 * Q_LORA / 4);
    gemm3_lds<<<dim3(QLD / 128, S / 128), 256, 0, stream>>>(qrh, qrl, wq2h, wq2l, qib, S, QLD, Q_LORA);
    // ---- rope ----
    rope_inter_kernel<<<S * NH * 32 / 256, 256, 0, stream>>>(qib, fcos, fsin, NH, QK_HD, QK_NOPE, QLD);
    rope_inter_kernel<<<S * 32 / 256, 256, 0, stream>>>(xp + 1536, fcos, fsin, 1, 0, KV_LORA, XPLD);
    // iq rope/rotate/wq only for s >= 1024 (iscore never reads query rows s < 1024: dense-causal there)
    rope_half_kernel<<<S * NH * 32 / 512, 256, 0, stream>>>(qib + 3072, fcos, fsin, NH, 128, QLD, 1024);
    // ---- indexer ----
    ln_kernel<<<S, 128, 0, stream>>>(xp + 2112, iknw, iknb, XPLD);
    rope_half_kernel<<<S * 32 / 256, 256, 0, stream>>>(xp + 2112, fcos, fsin, 1, 0, XPLD, 0);
    rotate_kernel<<<S * NH / 2, 128, 0, stream>>>(qib + 3072, QLD, NH, iqr, 1024 * NH);
    rotate_kernel<<<S, 128, 0, stream>>>(xp + 2112, XPLD, 1, ikr, 0);
    wq_kernel<<<S * NH * 128 / 512, 256, 0, stream>>>(xp + 2240, iqr, 1024 * NH * 128);
    iscore_mfma<<<dim3(16, 8), 256, 0, stream>>>(iqr, ikr, isc);
    topk_kernel<<<1024, 256, 0, stream>>>(isc, tk, 1024);
    // ---- attention prep (kvsplit/splitw2 after iscore: their buffers overlay iqr/ikr) ----
    w1t_kernel<<<dim3(8, 2, 16), 256, 0, stream>>>(kv_b, w1t);
    qabs_mfma<<<dim3(4, S / 128, 16), 256, 0, stream>>>(qib, w1t, qah, qal);
    qpe_split<<<S * NH * 64 / 256, 256, 0, stream>>>(qib, qah, qal);
    kvsplit_kernel<<<S, 576, 0, stream>>>(kv, xp + 1536, kvh, kvl, kvi);
    splitw2_kernel<<<1024, 256, 0, stream>>>(kv_b, w2h, w2l);
    // ---- attention chunks (c<2: s<1024 -> dense mode, no gather) ----
    for (int c = 0; c < 4; ++c) {
        int s0 = c * SCHUNK;
        int dense = (c < 2) ? 1 : 0;
        attn_score_mfma<<<dim3(SCHUNK, 4), 512, 0, stream>>>(qah, qal, kvh, kvl, tk, scb, s0, dense);
        softmax_pb<<<SCHUNK * 16, 256, 0, stream>>>(scb, pbh, pbl);
        attn_pv_mfma<<<SCHUNK, 512, 0, stream>>>(pbh, pbl, kvi, tk, o1h, o1l, s0, dense);
        outproj_mfma<<<dim3(4, 16), 256, 0, stream>>>(o1h, o1l, w2h, w2l, o2h, o2l, s0);
    }
    // ---- final projection: split o_proj into dead scb region, then pure-bf16x3 GEMM ----
    split_kernel<<<DIM * 2048 / 1024, 256, 0, stream>>>(o_proj, oph, opl, DIM * 2048 / 4);
    gemm3_lds<<<dim3(DIM / 128, S / 128), 256, 0, stream>>>(o2h, o2l, oph, opl, out, S, DIM, NH * V_HD);
}